// Round 17
// baseline (287.771 us; speedup 1.0000x reference)
//
#include <hip/hip_runtime.h>
#include <hip/hip_bf16.h>
#include <math.h>

typedef __attribute__((ext_vector_type(8))) __bf16 bf16x8;
typedef __attribute__((ext_vector_type(4))) __bf16 bf16x4;
typedef __attribute__((ext_vector_type(2))) __bf16 bf16x2;
typedef __attribute__((ext_vector_type(4))) float  f32x4;

#define MFMA16(a,b,c) __builtin_amdgcn_mfma_f32_16x16x32_bf16((a),(b),(c),0,0,0)

__device__ __forceinline__ unsigned pack2bf(float a, float b){
  bf16x2 t; t[0] = (__bf16)a; t[1] = (__bf16)b;
  return __builtin_bit_cast(unsigned, t);
}
__device__ __forceinline__ int perm1(int r){ return ((r<<2)|(r>>1)) & 7; }

__device__ __forceinline__ bf16x8 cvt8(const float4& a, const float4& b){
  bf16x8 h;
  h[0]=(__bf16)a.x; h[1]=(__bf16)a.y; h[2]=(__bf16)a.z; h[3]=(__bf16)a.w;
  h[4]=(__bf16)b.x; h[5]=(__bf16)b.y; h[6]=(__bf16)b.z; h[7]=(__bf16)b.w;
  return h;
}

// ---------------------------------------------------------------------------
// One-shot f32->bf16 weight conversion (verified R13).
// ---------------------------------------------------------------------------
__global__ __launch_bounds__(256) void cvt_weights(
    const float* __restrict__ w0, const float* __restrict__ w1,
    const float* __restrict__ w2, const float* __restrict__ w3,
    const float* __restrict__ w4, const float* __restrict__ w5,
    const float* __restrict__ w6, const float* __restrict__ w7,
    __bf16* __restrict__ dst)
{
  const int gid = blockIdx.x*256 + threadIdx.x;
  const float* src; int base, loc;
  if      (gid <  49152){ src = w0; base = 0;      loc = gid; }
  else if (gid <  65536){ src = w1; base = 196608; loc = gid -  49152; }
  else if (gid <  81920){ src = w2; base = 262144; loc = gid -  65536; }
  else if (gid <  98304){ src = w3; base = 327680; loc = gid -  81920; }
  else if (gid < 114688){ src = w4; base = 393216; loc = gid -  98304; }
  else if (gid < 131072){ src = w5; base = 458752; loc = gid - 114688; }
  else if (gid < 196608){ src = w6; base = 524288; loc = gid - 131072; }
  else                  { src = w7; base = 786432; loc = gid - 196608; }
  const float4 v = *(const float4*)&src[(size_t)loc*4];
  bf16x4 h; h[0]=(__bf16)v.x; h[1]=(__bf16)v.y; h[2]=(__bf16)v.z; h[3]=(__bf16)v.w;
  *(bf16x4*)&dst[(size_t)base + (size_t)loc*4] = h;
}

// ---------------------------------------------------------------------------
// Generic GEMM (verified R13).
// ---------------------------------------------------------------------------
template<int BM, bool RELU, int OUTMODE, int AMODE, int BMODE>
__global__ __launch_bounds__(256) void gemm_bt(
    const void* __restrict__ Av, const float* __restrict__ A2,
    const void* __restrict__ Wv,
    const float* __restrict__ bias, void* __restrict__ Cv,
    int M, int N, int K, int ldc, int coff, float oscale)
{
  constexpr int MT = BM/32;
  constexpr int PASSES = BM/64;
  __shared__ __align__(16) __bf16 As[BM][72];
  __shared__ __align__(16) __bf16 Bs[64][72];

  const int tid  = threadIdx.x;
  const int wid  = tid >> 6;
  const int lane = tid & 63;
  const int wr   = wid >> 1;
  const int wc   = wid & 1;
  const int lq   = lane & 15;
  const int lk8  = (lane >> 4) << 3;
  const int rb   = (lane >> 4) << 2;

  const int m0 = blockIdx.x * BM;
  const int n0 = blockIdx.y * 64;

  const int sr = tid >> 2;
  const int sc = (tid & 3) << 4;

  f32x4 acc[MT][2];
  #pragma unroll
  for (int i=0;i<MT;i++)
    #pragma unroll
    for (int j=0;j<2;j++) acc[i][j] = f32x4{0.f,0.f,0.f,0.f};

  for (int k0=0; k0<K; k0+=64){
    __syncthreads();
    #pragma unroll
    for (int p=0;p<PASSES;p++){
      const int row = sr + p*64;
      if (AMODE == 2){
        const __bf16* ap = (const __bf16*)Av + (size_t)(m0+row)*K + k0 + sc;
        *(bf16x8*)&As[row][sc]   = *(const bf16x8*)(ap);
        *(bf16x8*)&As[row][sc+8] = *(const bf16x8*)(ap + 8);
      } else {
        const float* ap = (const float*)Av + (size_t)(m0+row)*K + k0 + sc;
        float4 a0 = *(const float4*)(ap);
        float4 a1 = *(const float4*)(ap+4);
        float4 a2 = *(const float4*)(ap+8);
        float4 a3 = *(const float4*)(ap+12);
        if (AMODE == 1){
          const float* bp = A2 + (size_t)(m0+row)*K + k0 + sc;
          const float4 b0 = *(const float4*)(bp);
          const float4 b1 = *(const float4*)(bp+4);
          const float4 b2 = *(const float4*)(bp+8);
          const float4 b3 = *(const float4*)(bp+12);
          a0.x+=b0.x; a0.y+=b0.y; a0.z+=b0.z; a0.w+=b0.w;
          a1.x+=b1.x; a1.y+=b1.y; a1.z+=b1.z; a1.w+=b1.w;
          a2.x+=b2.x; a2.y+=b2.y; a2.z+=b2.z; a2.w+=b2.w;
          a3.x+=b3.x; a3.y+=b3.y; a3.z+=b3.z; a3.w+=b3.w;
        }
        *(bf16x8*)&As[row][sc]   = cvt8(a0,a1);
        *(bf16x8*)&As[row][sc+8] = cvt8(a2,a3);
      }
    }
    if (BMODE == 1){
      const __bf16* wp = (const __bf16*)Wv + (size_t)(n0+sr)*K + k0 + sc;
      *(bf16x8*)&Bs[sr][sc]   = *(const bf16x8*)(wp);
      *(bf16x8*)&Bs[sr][sc+8] = *(const bf16x8*)(wp + 8);
    } else {
      const float* wp = (const float*)Wv + (size_t)(n0+sr)*K + k0 + sc;
      const float4 a0 = *(const float4*)(wp);
      const float4 a1 = *(const float4*)(wp+4);
      const float4 a2 = *(const float4*)(wp+8);
      const float4 a3 = *(const float4*)(wp+12);
      *(bf16x8*)&Bs[sr][sc]   = cvt8(a0,a1);
      *(bf16x8*)&Bs[sr][sc+8] = cvt8(a2,a3);
    }
    __syncthreads();
    #pragma unroll
    for (int ksub=0; ksub<2; ksub++){
      bf16x8 bfr[2];
      #pragma unroll
      for (int j=0;j<2;j++)
        bfr[j] = *(const bf16x8*)&Bs[wc*32 + j*16 + lq][ksub*32 + lk8];
      #pragma unroll
      for (int i=0;i<MT;i++){
        const bf16x8 af = *(const bf16x8*)&As[wr*(BM/2) + i*16 + lq][ksub*32 + lk8];
        acc[i][0] = MFMA16(af, bfr[0], acc[i][0]);
        acc[i][1] = MFMA16(af, bfr[1], acc[i][1]);
      }
    }
  }

  #pragma unroll
  for (int i=0;i<MT;i++)
    #pragma unroll
    for (int j=0;j<2;j++){
      const int coln = n0 + wc*32 + j*16 + lq;
      const float bv = bias ? bias[coln] : 0.f;
      if (OUTMODE == 2){
        const int rowm0 = m0 + wr*(BM/2) + i*16 + rb;
        bf16x4 hv;
        #pragma unroll
        for (int r=0;r<4;r++){
          float vv = (acc[i][j][r] + bv) * oscale;
          if (RELU) vv = fmaxf(vv, 0.f);
          hv[r] = (__bf16)vv;
        }
        *(bf16x4*)&((__bf16*)Cv)[((size_t)((rowm0>>10)*256) + coln)*1024 + (rowm0&1023)] = hv;
      } else {
        #pragma unroll
        for (int r=0;r<4;r++){
          const int rowm = m0 + wr*(BM/2) + i*16 + rb + r;
          float vv = (acc[i][j][r] + bv) * oscale;
          if (RELU) vv = fmaxf(vv, 0.f);
          const size_t idx = (size_t)rowm*ldc + coff + coln;
          if (OUTMODE == 1) ((__bf16*)Cv)[idx] = (__bf16)vv;
          else              ((float*)Cv)[idx]  = vv;
        }
      }
    }
}

// ---------------------------------------------------------------------------
// Fused K/V projection from srcs (verified R11/R13).
// ---------------------------------------------------------------------------
__global__ __launch_bounds__(256) void gemm_srcs_kv(
    const float* __restrict__ S,
    const __bf16* __restrict__ Wk, const float* __restrict__ bk,
    const __bf16* __restrict__ Wv, const float* __restrict__ bv,
    __bf16* __restrict__ Kout, __bf16* __restrict__ Vt)
{
  extern __shared__ __bf16 lds[];
  __bf16* As = lds;              // [128][264]
  __bf16* Bs = lds + 128*264;    // [64][264]

  const int tid  = threadIdx.x;
  const int wid  = tid >> 6;
  const int lane = tid & 63;
  const int wr   = wid >> 1;
  const int wc   = wid & 1;
  const int lq   = lane & 15;
  const int lk8  = (lane >> 4) << 3;
  const int rb   = (lane >> 4) << 2;

  const int m0 = blockIdx.x * 128;
  const int bb = m0 >> 12;
  const int p0 = m0 & 4095;

  const int cA = tid & 31;
  const int qA = tid >> 5;
  for (int k0=0; k0<256; k0+=32){
    const float* sbase = &S[((size_t)bb*256 + k0 + cA)*4096 + p0];
    #pragma unroll
    for (int ps=0; ps<4; ps++){
      const int p = ps*32 + qA*4;
      const float4 f4 = *(const float4*)(sbase + p);
      As[(p+0)*264 + k0 + cA] = (__bf16)f4.x;
      As[(p+1)*264 + k0 + cA] = (__bf16)f4.y;
      As[(p+2)*264 + k0 + cA] = (__bf16)f4.z;
      As[(p+3)*264 + k0 + cA] = (__bf16)f4.w;
    }
  }

  const int sr  = tid >> 2;
  const int scb = (tid & 3) * 64;

  for (int half=0; half<2; half++){
    const __bf16* W   = half ? Wv : Wk;
    const float* bias = half ? bv : bk;
    for (int nt=0; nt<4; nt++){
      const int n0 = nt*64;
      __syncthreads();
      {
        const __bf16* wp = W + (size_t)(n0+sr)*256 + scb;
        #pragma unroll
        for (int j=0;j<4;j++){
          *(bf16x8*)&Bs[sr*264 + scb + j*16]     = *(const bf16x8*)(wp + j*16);
          *(bf16x8*)&Bs[sr*264 + scb + j*16 + 8] = *(const bf16x8*)(wp + j*16 + 8);
        }
      }
      __syncthreads();
      f32x4 acc[4][2];
      #pragma unroll
      for (int i=0;i<4;i++)
        #pragma unroll
        for (int j=0;j<2;j++) acc[i][j] = f32x4{0.f,0.f,0.f,0.f};
      #pragma unroll
      for (int k0=0; k0<256; k0+=32){
        bf16x8 bfr[2];
        #pragma unroll
        for (int j=0;j<2;j++)
          bfr[j] = *(const bf16x8*)&Bs[(wc*32 + j*16 + lq)*264 + k0 + lk8];
        #pragma unroll
        for (int i=0;i<4;i++){
          const bf16x8 af = *(const bf16x8*)&As[(wr*64 + i*16 + lq)*264 + k0 + lk8];
          acc[i][0] = MFMA16(af, bfr[0], acc[i][0]);
          acc[i][1] = MFMA16(af, bfr[1], acc[i][1]);
        }
      }
      #pragma unroll
      for (int i=0;i<4;i++)
        #pragma unroll
        for (int j=0;j<2;j++){
          const int coln = n0 + wc*32 + j*16 + lq;
          const float bvv = bias[coln];
          if (half){
            bf16x4 hv;
            #pragma unroll
            for (int r=0;r<4;r++) hv[r] = (__bf16)(acc[i][j][r] + bvv);
            *(bf16x4*)&Vt[((size_t)bb*256 + coln)*4096 + p0 + wr*64 + i*16 + rb] = hv;
          } else {
            #pragma unroll
            for (int r=0;r<4;r++){
              const int rowm = m0 + wr*64 + i*16 + rb + r;
              Kout[(size_t)rowm*256 + coln] = (__bf16)(acc[i][j][r] + bvv);
            }
          }
        }
    }
  }
}

// ---------------------------------------------------------------------------
__global__ __launch_bounds__(256) void ln_kernel(const float* __restrict__ res,
                                                 const float* __restrict__ x,
                                                 const float* __restrict__ g,
                                                 const float* __restrict__ beta,
                                                 float* __restrict__ out,
                                                 __bf16* __restrict__ outb)
{
  const int row  = blockIdx.x*4 + (threadIdx.x >> 6);
  const int lane = threadIdx.x & 63;
  const int c = lane*4;
  const float4 rv = *(const float4*)&res[(size_t)row*256 + c];
  const float4 xv = *(const float4*)&x[(size_t)row*256 + c];
  float v0=rv.x+xv.x, v1=rv.y+xv.y, v2=rv.z+xv.z, v3=rv.w+xv.w;
  float s = v0+v1+v2+v3;
  #pragma unroll
  for (int off=1; off<64; off<<=1) s += __shfl_xor(s, off);
  const float mean = s * (1.f/256.f);
  const float d0=v0-mean, d1=v1-mean, d2=v2-mean, d3=v3-mean;
  float q = d0*d0 + d1*d1 + d2*d2 + d3*d3;
  #pragma unroll
  for (int off=1; off<64; off<<=1) q += __shfl_xor(q, off);
  const float rstd = rsqrtf(q*(1.f/256.f) + 1e-5f);
  const float4 gv = *(const float4*)&g[c];
  const float4 bv = *(const float4*)&beta[c];
  float4 ov;
  ov.x = d0*rstd*gv.x + bv.x;
  ov.y = d1*rstd*gv.y + bv.y;
  ov.z = d2*rstd*gv.z + bv.z;
  ov.w = d3*rstd*gv.w + bv.w;
  *(float4*)&out[(size_t)row*256 + c] = ov;
  if (outb){
    bf16x4 hv;
    hv[0]=(__bf16)ov.x; hv[1]=(__bf16)ov.y; hv[2]=(__bf16)ov.z; hv[3]=(__bf16)ov.w;
    *(bf16x4*)&outb[(size_t)row*256 + c] = hv;
  }
}

// ---------------------------------------------------------------------------
// Flash self-attention (verified R10-R13).
// ---------------------------------------------------------------------------
__global__ __launch_bounds__(256) void flash_self(
    const __bf16* __restrict__ qks, const __bf16* __restrict__ vts,
    __bf16* __restrict__ sab)
{
  const int qt = blockIdx.x;
  const int b  = blockIdx.y >> 3;
  const int h  = blockIdx.y & 7;
  const int tid  = threadIdx.x;
  const int wid  = tid >> 6;
  const int lane = tid & 63;
  const int lq   = lane & 15;
  const int hi   = lane >> 4;
  const int lk8  = hi << 3;
  const int rb   = hi << 2;
  const float SCALE = 0.17677669529663687f;

  const int qrow = b*1024 + qt*64 + wid*16 + lq;
  const bf16x8 qf = *(const bf16x8*)&qks[(size_t)qrow*512 + h*32 + lk8];

  const __bf16* kb0 = &qks[(size_t)(b*1024 + lq)*512 + 256 + h*32 + lk8];
  const __bf16* vb0 = &vts[(size_t)(b*256 + h*32 + lq)*1024 + lk8];

  const f32x4 Z = {0.f, 0.f, 0.f, 0.f};
  float m = -1e30f, l = 0.f;
  f32x4 o0 = Z, o1 = Z;

  for (int it=0; it<16; ++it){
    const int key0 = it*64;
    f32x4 s4[4];
    #pragma unroll
    for (int kt=0;kt<4;kt++){
      const bf16x8 kf = *(const bf16x8*)(kb0 + (size_t)(key0 + kt*16)*512);
      s4[kt] = MFMA16(kf, qf, Z);
      #pragma unroll
      for (int r=0;r<4;r++) s4[kt][r] *= SCALE;
    }
    float pm = s4[0][0];
    #pragma unroll
    for (int kt=0;kt<4;kt++)
      #pragma unroll
      for (int r=0;r<4;r++) pm = fmaxf(pm, s4[kt][r]);
    pm = fmaxf(pm, __shfl_xor(pm,16));
    pm = fmaxf(pm, __shfl_xor(pm,32));
    if (!__all(pm <= m + 8.f)){
      const float mn = fmaxf(m, pm);
      const float alpha = __expf(m - mn);
      o0[0]*=alpha; o0[1]*=alpha; o0[2]*=alpha; o0[3]*=alpha;
      o1[0]*=alpha; o1[1]*=alpha; o1[2]*=alpha; o1[3]*=alpha;
      l *= alpha;
      m = mn;
    }
    float p[4][4]; float rs = 0.f;
    #pragma unroll
    for (int kt=0;kt<4;kt++)
      #pragma unroll
      for (int r=0;r<4;r++){ p[kt][r] = __expf(s4[kt][r]-m); rs += p[kt][r]; }
    rs += __shfl_xor(rs,16);
    rs += __shfl_xor(rs,32);
    l += rs;
    unsigned pk0[4], pk1[4];
    #pragma unroll
    for (int kt=0;kt<4;kt++){
      pk0[kt] = pack2bf(p[kt][0], p[kt][1]);
      pk1[kt] = pack2bf(p[kt][2], p[kt][3]);
    }
    const int srcA = ((hi&1)<<5) + lq;
    const int srcB = srcA + 16;
    const bool ksel = hi >= 2;
    bf16x8 pf[2];
    #pragma unroll
    for (int ks2=0; ks2<2; ks2++){
      const unsigned a0 = (unsigned)__shfl((int)pk0[2*ks2],   srcA);
      const unsigned a1 = (unsigned)__shfl((int)pk0[2*ks2+1], srcA);
      const unsigned b0 = (unsigned)__shfl((int)pk1[2*ks2],   srcA);
      const unsigned b1 = (unsigned)__shfl((int)pk1[2*ks2+1], srcA);
      const unsigned c0 = (unsigned)__shfl((int)pk0[2*ks2],   srcB);
      const unsigned c1 = (unsigned)__shfl((int)pk0[2*ks2+1], srcB);
      const unsigned d0 = (unsigned)__shfl((int)pk1[2*ks2],   srcB);
      const unsigned d1 = (unsigned)__shfl((int)pk1[2*ks2+1], srcB);
      union { unsigned u[4]; bf16x8 v; } uu;
      uu.u[0] = ksel ? a1 : a0;
      uu.u[1] = ksel ? b1 : b0;
      uu.u[2] = ksel ? c1 : c0;
      uu.u[3] = ksel ? d1 : d0;
      pf[ks2] = uu.v;
    }
    #pragma unroll
    for (int ks2=0; ks2<2; ks2++){
      const bf16x8 vf0 = *(const bf16x8*)(vb0 + key0 + ks2*32);
      const bf16x8 vf1 = *(const bf16x8*)(vb0 + (size_t)16*1024 + key0 + ks2*32);
      o0 = MFMA16(vf0, pf[ks2], o0);
      o1 = MFMA16(vf1, pf[ks2], o1);
    }
  }
  const float inv = 1.f / l;
  bf16x4 w0, w1;
  #pragma unroll
  for (int r=0;r<4;r++){ w0[r] = (__bf16)(o0[r]*inv); w1[r] = (__bf16)(o1[r]*inv); }
  *(bf16x4*)&sab[(size_t)qrow*256 + h*32 + rb]      = w0;
  *(bf16x4*)&sab[(size_t)qrow*256 + h*32 + 16 + rb] = w1;
}

// ---------------------------------------------------------------------------
// Flash cross-attention v8: R13 v6 body + T14 async K-prefetch
// (issue K(t+1) global loads before compute, LDS-write after the post-compute
// barrier; V stays synchronous). +32 VGPR, target <=256 for 2 waves/SIMD.
// ---------------------------------------------------------------------------
__global__ __launch_bounds__(256, 1) void flash_cross(
    const __bf16* __restrict__ qgm, const __bf16* __restrict__ kg,
    const __bf16* __restrict__ vtg, __bf16* __restrict__ Opart,
    float* __restrict__ ml)
{
  extern __shared__ __bf16 smem[];
  __bf16* Ks = smem;            // [64][256] perm1-swizzled 16B chunks
  __bf16* Vt = smem + 64*256;   // [256][64] perm1-swizzled 16B chunks

  const int bid = blockIdx.x;
  const int xcd = bid & 7;
  const int grp = bid >> 3;
  const int qt  = grp & 7;
  const int pp  = xcd + 8*(grp >> 3);
  const int b   = pp >> 3;
  const int sl  = pp & 7;

  const int tid  = threadIdx.x;
  const int wid  = tid >> 6;
  const int lane = tid & 63;
  const int lq   = lane & 15;
  const int hi   = lane >> 4;
  const int lk8  = hi << 3;
  const int rb   = hi << 2;
  const int p1l  = perm1(lq & 7);

  const int q0 = b*1024 + qt*128 + wid*32;
  bf16x8 qf[2][8];
  #pragma unroll
  for (int g=0; g<2; g++)
    #pragma unroll
    for (int ks=0; ks<8; ks++)
      qf[g][ks] = *(const bf16x8*)&qgm[(size_t)(q0 + g*16 + lq)*256 + ks*32 + lk8];

  const f32x4 Z = {0.f, 0.f, 0.f, 0.f};
  float m[2] = {-1e30f, -1e30f};
  float l[2] = {0.f, 0.f};
  f32x4 o[2][16];
  #pragma unroll
  for (int g=0; g<2; g++)
    #pragma unroll
    for (int nf=0; nf<16; nf++) o[g][nf] = Z;

  const int srow = tid >> 2;
  const int c4   = tid & 3;
  const int p1s  = perm1(srow & 7);

  // ---- prologue: stage tile 0 (sync) ----
  {
    const int key0 = sl*512;
    const __bf16* kb = &kg[(size_t)(b*4096 + key0 + srow)*256];
    #pragma unroll
    for (int j=0;j<8;j++){
      const int ch = c4 + j*4;
      *(bf16x8*)&Ks[srow*256 + ((ch ^ p1s)<<3)] = *(const bf16x8*)(kb + ch*8);
    }
    #pragma unroll
    for (int ps=0; ps<4; ps++){
      const int d = srow + ps*64;
      const __bf16* vb = &vtg[(size_t)(b*256 + d)*4096 + key0];
      #pragma unroll
      for (int s2=0;s2<2;s2++){
        const int ch = c4 + s2*4;
        *(bf16x8*)&Vt[d*64 + ((ch ^ p1s)<<3)] = *(const bf16x8*)(vb + ch*8);
      }
    }
  }
  __syncthreads();

  for (int it=0; it<8; ++it){
    const int key0n = sl*512 + (it+1)*64;
    // T14: issue next tile's K loads now; they fly during compute below.
    bf16x8 kreg[8];
    if (it < 7){
      const __bf16* kb = &kg[(size_t)(b*4096 + key0n + srow)*256];
      #pragma unroll
      for (int j=0;j<8;j++)
        kreg[j] = *(const bf16x8*)(kb + (c4 + j*4)*8);
    }
    // ---- compute on current tile ----
    f32x4 s4[2][4];
    #pragma unroll
    for (int g=0; g<2; g++)
      #pragma unroll
      for (int kt=0;kt<4;kt++) s4[g][kt] = Z;
    #pragma unroll
    for (int ks=0; ks<8; ks++){
      #pragma unroll
      for (int kt=0; kt<4; kt++){
        const bf16x8 kf = *(const bf16x8*)&Ks[(kt*16+lq)*256 + (((ks*4+hi) ^ p1l)<<3)];
        s4[0][kt] = MFMA16(kf, qf[0][ks], s4[0][kt]);
        s4[1][kt] = MFMA16(kf, qf[1][ks], s4[1][kt]);
      }
    }
    float pm[2];
    #pragma unroll
    for (int g=0; g<2; g++){
      float v = s4[g][0][0];
      #pragma unroll
      for (int kt=0;kt<4;kt++)
        #pragma unroll
        for (int r=0;r<4;r++) v = fmaxf(v, s4[g][kt][r]);
      v = fmaxf(v, __shfl_xor(v, 16));
      v = fmaxf(v, __shfl_xor(v, 32));
      pm[g] = v;
    }
    const bool need = (pm[0] > m[0] + 8.f) || (pm[1] > m[1] + 8.f);
    if (__any(need)){
      #pragma unroll
      for (int g=0; g<2; g++){
        const float mn = fmaxf(m[g], pm[g]);
        const float alpha = __expf(m[g] - mn);
        #pragma unroll
        for (int nf=0;nf<16;nf++){
          o[g][nf][0]*=alpha; o[g][nf][1]*=alpha;
          o[g][nf][2]*=alpha; o[g][nf][3]*=alpha;
        }
        l[g] *= alpha;
        m[g] = mn;
      }
    }
    bf16x8 pf[2][2];
    #pragma unroll
    for (int g=0; g<2; g++){
      float p[4][4];
      float rs = 0.f;
      #pragma unroll
      for (int kt=0;kt<4;kt++)
        #pragma unroll
        for (int r=0;r<4;r++){ p[kt][r] = __expf(s4[g][kt][r] - m[g]); rs += p[kt][r]; }
      rs += __shfl_xor(rs, 16);
      rs += __shfl_xor(rs, 32);
      l[g] += rs;
      unsigned pk0[4], pk1[4];
      #pragma unroll
      for (int kt=0;kt<4;kt++){
        pk0[kt] = pack2bf(p[kt][0], p[kt][1]);
        pk1[kt] = pack2bf(p[kt][2], p[kt][3]);
      }
      const int srcA = ((hi&1)<<5) + lq;
      const int srcB = srcA + 16;
      const bool ksel = hi >= 2;
      #pragma unroll
      for (int ks2=0; ks2<2; ks2++){
        const unsigned a0 = (unsigned)__shfl((int)pk0[2*ks2],   srcA);
        const unsigned a1 = (unsigned)__shfl((int)pk0[2*ks2+1], srcA);
        const unsigned b0 = (unsigned)__shfl((int)pk1[2*ks2],   srcA);
        const unsigned b1 = (unsigned)__shfl((int)pk1[2*ks2+1], srcA);
        const unsigned c0 = (unsigned)__shfl((int)pk0[2*ks2],   srcB);
        const unsigned c1 = (unsigned)__shfl((int)pk0[2*ks2+1], srcB);
        const unsigned d0 = (unsigned)__shfl((int)pk1[2*ks2],   srcB);
        const unsigned d1 = (unsigned)__shfl((int)pk1[2*ks2+1], srcB);
        union { unsigned u[4]; bf16x8 v; } uu;
        uu.u[0] = ksel ? a1 : a0;
        uu.u[1] = ksel ? b1 : b0;
        uu.u[2] = ksel ? c1 : c0;
        uu.u[3] = ksel ? d1 : d0;
        pf[g][ks2] = uu.v;
      }
    }
    #pragma unroll
    for (int nf=0; nf<16; nf++){
      #pragma unroll
      for (int ks2=0; ks2<2; ks2++){
        const bf16x8 af = *(const bf16x8*)&Vt[(nf*16+lq)*64 + (((ks2*4+hi) ^ p1l)<<3)];
        o[0][nf] = MFMA16(af, pf[0][ks2], o[0][nf]);
        o[1][nf] = MFMA16(af, pf[1][ks2], o[1][nf]);
      }
    }
    // ---- stage next tile: write prefetched K, sync-load V ----
    if (it < 7){
      __syncthreads();   // all LDS reads of current tile done
      #pragma unroll
      for (int j=0;j<8;j++){
        const int ch = c4 + j*4;
        *(bf16x8*)&Ks[srow*256 + ((ch ^ p1s)<<3)] = kreg[j];
      }
      #pragma unroll
      for (int ps=0; ps<4; ps++){
        const int d = srow + ps*64;
        const __bf16* vb = &vtg[(size_t)(b*256 + d)*4096 + key0n];
        #pragma unroll
        for (int s2=0;s2<2;s2++){
          const int ch = c4 + s2*4;
          *(bf16x8*)&Vt[d*64 + ((ch ^ p1s)<<3)] = *(const bf16x8*)(vb + ch*8);
        }
      }
      __syncthreads();   // next tile ready
    }
  }
  #pragma unroll
  for (int g=0; g<2; g++){
    const int row = q0 + g*16 + lq;
    if (hi == 0){
      ml[(size_t)(sl*8192 + row)*2 + 0] = m[g];
      ml[(size_t)(sl*8192 + row)*2 + 1] = l[g];
    }
    #pragma unroll
    for (int nf=0; nf<16; nf++){
      bf16x4 hv;
      #pragma unroll
      for (int r=0;r<4;r++) hv[r] = (__bf16)o[g][nf][r];
      *(bf16x4*)&Opart[(size_t)(sl*8192 + row)*256 + nf*16 + rb] = hv;
    }
  }
}

// ---------------------------------------------------------------------------
__global__ __launch_bounds__(256) void combine_kernel(const __bf16* __restrict__ Opart,
                                                      const float* __restrict__ ml,
                                                      __bf16* __restrict__ out)
{
  const int row = blockIdx.x;
  const int d = threadIdx.x;
  float mm[8], ll[8];
  #pragma unroll
  for (int s=0;s<8;s++){
    mm[s] = ml[(size_t)(s*8192+row)*2 + 0];
    ll[s] = ml[(size_t)(s*8192+row)*2 + 1];
  }
  float M = mm[0];
  #pragma unroll
  for (int s=1;s<8;s++) M = fmaxf(M, mm[s]);
  float L = 0.f, acc = 0.f;
  #pragma unroll
  for (int s=0;s<8;s++){
    const float e = __expf(mm[s]-M);
    L   += ll[s]*e;
    acc += e * (float)Opart[(size_t)(s*8192+row)*256 + d];
  }
  out[(size_t)row*256 + d] = (__bf16)(acc / L);
}

// ---------------------------------------------------------------------------
extern "C" void kernel_launch(void* const* d_in, const int* in_sizes, int n_in,
                              void* d_out, int out_size, void* d_ws, size_t ws_size,
                              hipStream_t stream)
{
  (void)in_sizes; (void)n_in; (void)out_size; (void)ws_size;
  const float* tgt        = (const float*)d_in[0];
  const float* srcs       = (const float*)d_in[2];
  const float* posemb     = (const float*)d_in[3];
  const float* in_proj_w  = (const float*)d_in[4];
  const float* in_proj_b  = (const float*)d_in[5];
  const float* out_proj_w = (const float*)d_in[6];
  const float* out_proj_b = (const float*)d_in[7];
  const float* lin_q_w    = (const float*)d_in[8];
  const float* lin_q_b    = (const float*)d_in[9];
  const float* lin_k_w    = (const float*)d_in[10];
  const float* lin_k_b    = (const float*)d_in[11];
  const float* lin_v_w    = (const float*)d_in[12];
  const float* lin_v_b    = (const float*)d_in[13];
  const float* lin_o_w    = (const float*)d_in[14];
  const float* lin_o_b    = (const float*)d_in[15];
  const float* norm1_g    = (const float*)d_in[16];
  const float* norm1_b    = (const float*)d_in[17];
  const float* norm2_g    = (const float*)d_in[18];
  const float* norm2_b    = (const float*)d_in[19];
  const float* ffn_w1     = (const float*)d_in[20];
  const float* ffn_b1     = (const float*)d_in[21];
  const float* ffn_w2     = (const float*)d_in[22];
  const float* ffn_b2     = (const float*)d_in[23];
  const float* ffn_norm_g = (const float*)d_in[24];
  const float* ffn_norm_b = (const float*)d_in[25];
  float* out = (float*)d_out;

  char* w = (char*)d_ws;
  const size_t MB = (size_t)1 << 20;
  // Region plan (R13-audited):
  float*  tgt1    = (float*)(w + 0);
  __bf16* qk_s    = (__bf16*)(w + 8*MB);
  __bf16* query_b = (__bf16*)(w + 8*MB);
  __bf16* tgt1b   = (__bf16*)(w + 12*MB);
  __bf16* attn2   = (__bf16*)(w + 12*MB);
  __bf16* v_t     = (__bf16*)(w + 16*MB);
  __bf16* key_b   = (__bf16*)(w + 16*MB);
  float*  t2proj  = (float*)(w + 16*MB);
  __bf16* sa_b    = (__bf16*)(w + 20*MB);
  float*  saproj  = (float*)(w + 24*MB);
  float*  tgt3    = (float*)(w + 24*MB);
  __bf16* val_t   = (__bf16*)(w + 32*MB);
  __bf16* ffn_h   = (__bf16*)(w + 32*MB);
  __bf16* Opart   = (__bf16*)(w + 48*MB);
  float*  ffn_out = (float*)(w + 48*MB);
  __bf16* tgt3b   = (__bf16*)(w + 56*MB);
  float*  ml      = (float*)(w + 80*MB);
  __bf16* wb      = (__bf16*)(w + 81*MB);

  __bf16* wb_inproj = wb;
  __bf16* wb_outp   = wb + 196608;
  __bf16* wb_q      = wb + 262144;
  __bf16* wb_k      = wb + 327680;
  __bf16* wb_v      = wb + 393216;
  __bf16* wb_o      = wb + 458752;
  __bf16* wb_ff1    = wb + 524288;
  __bf16* wb_ff2    = wb + 786432;

  // 0: one-shot weight conversion
  cvt_weights<<<1024,256,0,stream>>>(in_proj_w, out_proj_w, lin_q_w, lin_k_w,
      lin_v_w, lin_o_w, ffn_w1, ffn_w2, wb);

  // ---- Stage A: self-attention ----
  gemm_bt<64,false,1,1,1><<<dim3(128,8),256,0,stream>>>(tgt, posemb,
      wb_inproj, in_proj_b, qk_s, 8192,512,256, 512,0, 1.f);
  gemm_bt<64,false,2,0,1><<<dim3(128,4),256,0,stream>>>(tgt, nullptr,
      wb_inproj + (size_t)512*256, in_proj_b + 512, v_t, 8192,256,256, 256,0, 1.f);
  flash_self<<<dim3(16,64),256,0,stream>>>(qk_s, v_t, sa_b);
  gemm_bt<64,false,0,2,1><<<dim3(128,4),256,0,stream>>>(sa_b, nullptr,
      wb_outp, out_proj_b, saproj, 8192,256,256, 256,0, 1.f);
  ln_kernel<<<2048,256,0,stream>>>(tgt, saproj, norm2_g, norm2_b, tgt1, tgt1b);

  // ---- Stage B: cross-attention ----
  gemm_bt<64,false,1,2,1><<<dim3(128,4),256,0,stream>>>(tgt1b, nullptr,
      wb_q, lin_q_b, query_b, 8192,256,256, 256,0, 1.f);
  gemm_srcs_kv<<<256,256,(128+64)*264*2,stream>>>(srcs,
      wb_k, lin_k_b, wb_v, lin_v_b, key_b, val_t);
  flash_cross<<<512,256,65536,stream>>>(query_b, key_b, val_t, Opart, ml);
  combine_kernel<<<8192,256,0,stream>>>(Opart, ml, attn2);
  gemm_bt<64,false,0,2,1><<<dim3(128,4),256,0,stream>>>(attn2, nullptr,
      wb_o, lin_o_b, t2proj, 8192,256,256, 256,0, 1.f);
  ln_kernel<<<2048,256,0,stream>>>(tgt1, t2proj, norm1_g, norm1_b, tgt3, tgt3b);

  // ---- Stage C: FFN ----
  gemm_bt<128,true,1,2,1><<<dim3(64,16),256,0,stream>>>(tgt3b, nullptr,
      wb_ff1, ffn_b1, ffn_h, 8192,1024,256, 1024,0, 1.f);
  gemm_bt<64,false,0,2,1><<<dim3(128,4),256,0,stream>>>(ffn_h, nullptr,
      wb_ff2, ffn_b2, ffn_out, 8192,256,1024, 256,0, 1.f);
  ln_kernel<<<2048,256,0,stream>>>(tgt3, ffn_out, ffn_norm_g, ffn_norm_b, out, nullptr);
}

// Round 18
// 280.682 us; speedup vs baseline: 1.0253x; 1.0253x over previous
//
#include <hip/hip_runtime.h>
#include <hip/hip_bf16.h>
#include <math.h>

typedef __attribute__((ext_vector_type(8))) __bf16 bf16x8;
typedef __attribute__((ext_vector_type(4))) __bf16 bf16x4;
typedef __attribute__((ext_vector_type(2))) __bf16 bf16x2;
typedef __attribute__((ext_vector_type(4))) float  f32x4;

#define MFMA16(a,b,c) __builtin_amdgcn_mfma_f32_16x16x32_bf16((a),(b),(c),0,0,0)

__device__ __forceinline__ unsigned pack2bf(float a, float b){
  bf16x2 t; t[0] = (__bf16)a; t[1] = (__bf16)b;
  return __builtin_bit_cast(unsigned, t);
}
__device__ __forceinline__ int perm1(int r){ return ((r<<2)|(r>>1)) & 7; }

__device__ __forceinline__ bf16x8 cvt8(const float4& a, const float4& b){
  bf16x8 h;
  h[0]=(__bf16)a.x; h[1]=(__bf16)a.y; h[2]=(__bf16)a.z; h[3]=(__bf16)a.w;
  h[4]=(__bf16)b.x; h[5]=(__bf16)b.y; h[6]=(__bf16)b.z; h[7]=(__bf16)b.w;
  return h;
}

// ---------------------------------------------------------------------------
// One-shot f32->bf16 weight conversion (verified R13).
// ---------------------------------------------------------------------------
__global__ __launch_bounds__(256) void cvt_weights(
    const float* __restrict__ w0, const float* __restrict__ w1,
    const float* __restrict__ w2, const float* __restrict__ w3,
    const float* __restrict__ w4, const float* __restrict__ w5,
    const float* __restrict__ w6, const float* __restrict__ w7,
    __bf16* __restrict__ dst)
{
  const int gid = blockIdx.x*256 + threadIdx.x;
  const float* src; int base, loc;
  if      (gid <  49152){ src = w0; base = 0;      loc = gid; }
  else if (gid <  65536){ src = w1; base = 196608; loc = gid -  49152; }
  else if (gid <  81920){ src = w2; base = 262144; loc = gid -  65536; }
  else if (gid <  98304){ src = w3; base = 327680; loc = gid -  81920; }
  else if (gid < 114688){ src = w4; base = 393216; loc = gid -  98304; }
  else if (gid < 131072){ src = w5; base = 458752; loc = gid - 114688; }
  else if (gid < 196608){ src = w6; base = 524288; loc = gid - 131072; }
  else                  { src = w7; base = 786432; loc = gid - 196608; }
  const float4 v = *(const float4*)&src[(size_t)loc*4];
  bf16x4 h; h[0]=(__bf16)v.x; h[1]=(__bf16)v.y; h[2]=(__bf16)v.z; h[3]=(__bf16)v.w;
  *(bf16x4*)&dst[(size_t)base + (size_t)loc*4] = h;
}

// ---------------------------------------------------------------------------
// Generic GEMM (verified R13).
// ---------------------------------------------------------------------------
template<int BM, bool RELU, int OUTMODE, int AMODE, int BMODE>
__global__ __launch_bounds__(256) void gemm_bt(
    const void* __restrict__ Av, const float* __restrict__ A2,
    const void* __restrict__ Wv,
    const float* __restrict__ bias, void* __restrict__ Cv,
    int M, int N, int K, int ldc, int coff, float oscale)
{
  constexpr int MT = BM/32;
  constexpr int PASSES = BM/64;
  __shared__ __align__(16) __bf16 As[BM][72];
  __shared__ __align__(16) __bf16 Bs[64][72];

  const int tid  = threadIdx.x;
  const int wid  = tid >> 6;
  const int lane = tid & 63;
  const int wr   = wid >> 1;
  const int wc   = wid & 1;
  const int lq   = lane & 15;
  const int lk8  = (lane >> 4) << 3;
  const int rb   = (lane >> 4) << 2;

  const int m0 = blockIdx.x * BM;
  const int n0 = blockIdx.y * 64;

  const int sr = tid >> 2;
  const int sc = (tid & 3) << 4;

  f32x4 acc[MT][2];
  #pragma unroll
  for (int i=0;i<MT;i++)
    #pragma unroll
    for (int j=0;j<2;j++) acc[i][j] = f32x4{0.f,0.f,0.f,0.f};

  for (int k0=0; k0<K; k0+=64){
    __syncthreads();
    #pragma unroll
    for (int p=0;p<PASSES;p++){
      const int row = sr + p*64;
      if (AMODE == 2){
        const __bf16* ap = (const __bf16*)Av + (size_t)(m0+row)*K + k0 + sc;
        *(bf16x8*)&As[row][sc]   = *(const bf16x8*)(ap);
        *(bf16x8*)&As[row][sc+8] = *(const bf16x8*)(ap + 8);
      } else {
        const float* ap = (const float*)Av + (size_t)(m0+row)*K + k0 + sc;
        float4 a0 = *(const float4*)(ap);
        float4 a1 = *(const float4*)(ap+4);
        float4 a2 = *(const float4*)(ap+8);
        float4 a3 = *(const float4*)(ap+12);
        if (AMODE == 1){
          const float* bp = A2 + (size_t)(m0+row)*K + k0 + sc;
          const float4 b0 = *(const float4*)(bp);
          const float4 b1 = *(const float4*)(bp+4);
          const float4 b2 = *(const float4*)(bp+8);
          const float4 b3 = *(const float4*)(bp+12);
          a0.x+=b0.x; a0.y+=b0.y; a0.z+=b0.z; a0.w+=b0.w;
          a1.x+=b1.x; a1.y+=b1.y; a1.z+=b1.z; a1.w+=b1.w;
          a2.x+=b2.x; a2.y+=b2.y; a2.z+=b2.z; a2.w+=b2.w;
          a3.x+=b3.x; a3.y+=b3.y; a3.z+=b3.z; a3.w+=b3.w;
        }
        *(bf16x8*)&As[row][sc]   = cvt8(a0,a1);
        *(bf16x8*)&As[row][sc+8] = cvt8(a2,a3);
      }
    }
    if (BMODE == 1){
      const __bf16* wp = (const __bf16*)Wv + (size_t)(n0+sr)*K + k0 + sc;
      *(bf16x8*)&Bs[sr][sc]   = *(const bf16x8*)(wp);
      *(bf16x8*)&Bs[sr][sc+8] = *(const bf16x8*)(wp + 8);
    } else {
      const float* wp = (const float*)Wv + (size_t)(n0+sr)*K + k0 + sc;
      const float4 a0 = *(const float4*)(wp);
      const float4 a1 = *(const float4*)(wp+4);
      const float4 a2 = *(const float4*)(wp+8);
      const float4 a3 = *(const float4*)(wp+12);
      *(bf16x8*)&Bs[sr][sc]   = cvt8(a0,a1);
      *(bf16x8*)&Bs[sr][sc+8] = cvt8(a2,a3);
    }
    __syncthreads();
    #pragma unroll
    for (int ksub=0; ksub<2; ksub++){
      bf16x8 bfr[2];
      #pragma unroll
      for (int j=0;j<2;j++)
        bfr[j] = *(const bf16x8*)&Bs[wc*32 + j*16 + lq][ksub*32 + lk8];
      #pragma unroll
      for (int i=0;i<MT;i++){
        const bf16x8 af = *(const bf16x8*)&As[wr*(BM/2) + i*16 + lq][ksub*32 + lk8];
        acc[i][0] = MFMA16(af, bfr[0], acc[i][0]);
        acc[i][1] = MFMA16(af, bfr[1], acc[i][1]);
      }
    }
  }

  #pragma unroll
  for (int i=0;i<MT;i++)
    #pragma unroll
    for (int j=0;j<2;j++){
      const int coln = n0 + wc*32 + j*16 + lq;
      const float bv = bias ? bias[coln] : 0.f;
      if (OUTMODE == 2){
        const int rowm0 = m0 + wr*(BM/2) + i*16 + rb;
        bf16x4 hv;
        #pragma unroll
        for (int r=0;r<4;r++){
          float vv = (acc[i][j][r] + bv) * oscale;
          if (RELU) vv = fmaxf(vv, 0.f);
          hv[r] = (__bf16)vv;
        }
        *(bf16x4*)&((__bf16*)Cv)[((size_t)((rowm0>>10)*256) + coln)*1024 + (rowm0&1023)] = hv;
      } else {
        #pragma unroll
        for (int r=0;r<4;r++){
          const int rowm = m0 + wr*(BM/2) + i*16 + rb + r;
          float vv = (acc[i][j][r] + bv) * oscale;
          if (RELU) vv = fmaxf(vv, 0.f);
          const size_t idx = (size_t)rowm*ldc + coff + coln;
          if (OUTMODE == 1) ((__bf16*)Cv)[idx] = (__bf16)vv;
          else              ((float*)Cv)[idx]  = vv;
        }
      }
    }
}

// ---------------------------------------------------------------------------
// Fused K/V projection from srcs (verified R11/R13).
// ---------------------------------------------------------------------------
__global__ __launch_bounds__(256) void gemm_srcs_kv(
    const float* __restrict__ S,
    const __bf16* __restrict__ Wk, const float* __restrict__ bk,
    const __bf16* __restrict__ Wv, const float* __restrict__ bv,
    __bf16* __restrict__ Kout, __bf16* __restrict__ Vt)
{
  extern __shared__ __bf16 lds[];
  __bf16* As = lds;              // [128][264]
  __bf16* Bs = lds + 128*264;    // [64][264]

  const int tid  = threadIdx.x;
  const int wid  = tid >> 6;
  const int lane = tid & 63;
  const int wr   = wid >> 1;
  const int wc   = wid & 1;
  const int lq   = lane & 15;
  const int lk8  = (lane >> 4) << 3;
  const int rb   = (lane >> 4) << 2;

  const int m0 = blockIdx.x * 128;
  const int bb = m0 >> 12;
  const int p0 = m0 & 4095;

  const int cA = tid & 31;
  const int qA = tid >> 5;
  for (int k0=0; k0<256; k0+=32){
    const float* sbase = &S[((size_t)bb*256 + k0 + cA)*4096 + p0];
    #pragma unroll
    for (int ps=0; ps<4; ps++){
      const int p = ps*32 + qA*4;
      const float4 f4 = *(const float4*)(sbase + p);
      As[(p+0)*264 + k0 + cA] = (__bf16)f4.x;
      As[(p+1)*264 + k0 + cA] = (__bf16)f4.y;
      As[(p+2)*264 + k0 + cA] = (__bf16)f4.z;
      As[(p+3)*264 + k0 + cA] = (__bf16)f4.w;
    }
  }

  const int sr  = tid >> 2;
  const int scb = (tid & 3) * 64;

  for (int half=0; half<2; half++){
    const __bf16* W   = half ? Wv : Wk;
    const float* bias = half ? bv : bk;
    for (int nt=0; nt<4; nt++){
      const int n0 = nt*64;
      __syncthreads();
      {
        const __bf16* wp = W + (size_t)(n0+sr)*256 + scb;
        #pragma unroll
        for (int j=0;j<4;j++){
          *(bf16x8*)&Bs[sr*264 + scb + j*16]     = *(const bf16x8*)(wp + j*16);
          *(bf16x8*)&Bs[sr*264 + scb + j*16 + 8] = *(const bf16x8*)(wp + j*16 + 8);
        }
      }
      __syncthreads();
      f32x4 acc[4][2];
      #pragma unroll
      for (int i=0;i<4;i++)
        #pragma unroll
        for (int j=0;j<2;j++) acc[i][j] = f32x4{0.f,0.f,0.f,0.f};
      #pragma unroll
      for (int k0=0; k0<256; k0+=32){
        bf16x8 bfr[2];
        #pragma unroll
        for (int j=0;j<2;j++)
          bfr[j] = *(const bf16x8*)&Bs[(wc*32 + j*16 + lq)*264 + k0 + lk8];
        #pragma unroll
        for (int i=0;i<4;i++){
          const bf16x8 af = *(const bf16x8*)&As[(wr*64 + i*16 + lq)*264 + k0 + lk8];
          acc[i][0] = MFMA16(af, bfr[0], acc[i][0]);
          acc[i][1] = MFMA16(af, bfr[1], acc[i][1]);
        }
      }
      #pragma unroll
      for (int i=0;i<4;i++)
        #pragma unroll
        for (int j=0;j<2;j++){
          const int coln = n0 + wc*32 + j*16 + lq;
          const float bvv = bias[coln];
          if (half){
            bf16x4 hv;
            #pragma unroll
            for (int r=0;r<4;r++) hv[r] = (__bf16)(acc[i][j][r] + bvv);
            *(bf16x4*)&Vt[((size_t)bb*256 + coln)*4096 + p0 + wr*64 + i*16 + rb] = hv;
          } else {
            #pragma unroll
            for (int r=0;r<4;r++){
              const int rowm = m0 + wr*64 + i*16 + rb + r;
              Kout[(size_t)rowm*256 + coln] = (__bf16)(acc[i][j][r] + bvv);
            }
          }
        }
    }
  }
}

// ---------------------------------------------------------------------------
__global__ __launch_bounds__(256) void ln_kernel(const float* __restrict__ res,
                                                 const float* __restrict__ x,
                                                 const float* __restrict__ g,
                                                 const float* __restrict__ beta,
                                                 float* __restrict__ out,
                                                 __bf16* __restrict__ outb)
{
  const int row  = blockIdx.x*4 + (threadIdx.x >> 6);
  const int lane = threadIdx.x & 63;
  const int c = lane*4;
  const float4 rv = *(const float4*)&res[(size_t)row*256 + c];
  const float4 xv = *(const float4*)&x[(size_t)row*256 + c];
  float v0=rv.x+xv.x, v1=rv.y+xv.y, v2=rv.z+xv.z, v3=rv.w+xv.w;
  float s = v0+v1+v2+v3;
  #pragma unroll
  for (int off=1; off<64; off<<=1) s += __shfl_xor(s, off);
  const float mean = s * (1.f/256.f);
  const float d0=v0-mean, d1=v1-mean, d2=v2-mean, d3=v3-mean;
  float q = d0*d0 + d1*d1 + d2*d2 + d3*d3;
  #pragma unroll
  for (int off=1; off<64; off<<=1) q += __shfl_xor(q, off);
  const float rstd = rsqrtf(q*(1.f/256.f) + 1e-5f);
  const float4 gv = *(const float4*)&g[c];
  const float4 bv = *(const float4*)&beta[c];
  float4 ov;
  ov.x = d0*rstd*gv.x + bv.x;
  ov.y = d1*rstd*gv.y + bv.y;
  ov.z = d2*rstd*gv.z + bv.z;
  ov.w = d3*rstd*gv.w + bv.w;
  *(float4*)&out[(size_t)row*256 + c] = ov;
  if (outb){
    bf16x4 hv;
    hv[0]=(__bf16)ov.x; hv[1]=(__bf16)ov.y; hv[2]=(__bf16)ov.z; hv[3]=(__bf16)ov.w;
    *(bf16x4*)&outb[(size_t)row*256 + c] = hv;
  }
}

// ---------------------------------------------------------------------------
// Flash self-attention (verified R10-R13).
// ---------------------------------------------------------------------------
__global__ __launch_bounds__(256) void flash_self(
    const __bf16* __restrict__ qks, const __bf16* __restrict__ vts,
    __bf16* __restrict__ sab)
{
  const int qt = blockIdx.x;
  const int b  = blockIdx.y >> 3;
  const int h  = blockIdx.y & 7;
  const int tid  = threadIdx.x;
  const int wid  = tid >> 6;
  const int lane = tid & 63;
  const int lq   = lane & 15;
  const int hi   = lane >> 4;
  const int lk8  = hi << 3;
  const int rb   = hi << 2;
  const float SCALE = 0.17677669529663687f;

  const int qrow = b*1024 + qt*64 + wid*16 + lq;
  const bf16x8 qf = *(const bf16x8*)&qks[(size_t)qrow*512 + h*32 + lk8];

  const __bf16* kb0 = &qks[(size_t)(b*1024 + lq)*512 + 256 + h*32 + lk8];
  const __bf16* vb0 = &vts[(size_t)(b*256 + h*32 + lq)*1024 + lk8];

  const f32x4 Z = {0.f, 0.f, 0.f, 0.f};
  float m = -1e30f, l = 0.f;
  f32x4 o0 = Z, o1 = Z;

  for (int it=0; it<16; ++it){
    const int key0 = it*64;
    f32x4 s4[4];
    #pragma unroll
    for (int kt=0;kt<4;kt++){
      const bf16x8 kf = *(const bf16x8*)(kb0 + (size_t)(key0 + kt*16)*512);
      s4[kt] = MFMA16(kf, qf, Z);
      #pragma unroll
      for (int r=0;r<4;r++) s4[kt][r] *= SCALE;
    }
    float pm = s4[0][0];
    #pragma unroll
    for (int kt=0;kt<4;kt++)
      #pragma unroll
      for (int r=0;r<4;r++) pm = fmaxf(pm, s4[kt][r]);
    pm = fmaxf(pm, __shfl_xor(pm,16));
    pm = fmaxf(pm, __shfl_xor(pm,32));
    if (!__all(pm <= m + 8.f)){
      const float mn = fmaxf(m, pm);
      const float alpha = __expf(m - mn);
      o0[0]*=alpha; o0[1]*=alpha; o0[2]*=alpha; o0[3]*=alpha;
      o1[0]*=alpha; o1[1]*=alpha; o1[2]*=alpha; o1[3]*=alpha;
      l *= alpha;
      m = mn;
    }
    float p[4][4]; float rs = 0.f;
    #pragma unroll
    for (int kt=0;kt<4;kt++)
      #pragma unroll
      for (int r=0;r<4;r++){ p[kt][r] = __expf(s4[kt][r]-m); rs += p[kt][r]; }
    rs += __shfl_xor(rs,16);
    rs += __shfl_xor(rs,32);
    l += rs;
    unsigned pk0[4], pk1[4];
    #pragma unroll
    for (int kt=0;kt<4;kt++){
      pk0[kt] = pack2bf(p[kt][0], p[kt][1]);
      pk1[kt] = pack2bf(p[kt][2], p[kt][3]);
    }
    const int srcA = ((hi&1)<<5) + lq;
    const int srcB = srcA + 16;
    const bool ksel = hi >= 2;
    bf16x8 pf[2];
    #pragma unroll
    for (int ks2=0; ks2<2; ks2++){
      const unsigned a0 = (unsigned)__shfl((int)pk0[2*ks2],   srcA);
      const unsigned a1 = (unsigned)__shfl((int)pk0[2*ks2+1], srcA);
      const unsigned b0 = (unsigned)__shfl((int)pk1[2*ks2],   srcA);
      const unsigned b1 = (unsigned)__shfl((int)pk1[2*ks2+1], srcA);
      const unsigned c0 = (unsigned)__shfl((int)pk0[2*ks2],   srcB);
      const unsigned c1 = (unsigned)__shfl((int)pk0[2*ks2+1], srcB);
      const unsigned d0 = (unsigned)__shfl((int)pk1[2*ks2],   srcB);
      const unsigned d1 = (unsigned)__shfl((int)pk1[2*ks2+1], srcB);
      union { unsigned u[4]; bf16x8 v; } uu;
      uu.u[0] = ksel ? a1 : a0;
      uu.u[1] = ksel ? b1 : b0;
      uu.u[2] = ksel ? c1 : c0;
      uu.u[3] = ksel ? d1 : d0;
      pf[ks2] = uu.v;
    }
    #pragma unroll
    for (int ks2=0; ks2<2; ks2++){
      const bf16x8 vf0 = *(const bf16x8*)(vb0 + key0 + ks2*32);
      const bf16x8 vf1 = *(const bf16x8*)(vb0 + (size_t)16*1024 + key0 + ks2*32);
      o0 = MFMA16(vf0, pf[ks2], o0);
      o1 = MFMA16(vf1, pf[ks2], o1);
    }
  }
  const float inv = 1.f / l;
  bf16x4 w0, w1;
  #pragma unroll
  for (int r=0;r<4;r++){ w0[r] = (__bf16)(o0[r]*inv); w1[r] = (__bf16)(o1[r]*inv); }
  *(bf16x4*)&sab[(size_t)qrow*256 + h*32 + rb]      = w0;
  *(bf16x4*)&sab[(size_t)qrow*256 + h*32 + 16 + rb] = w1;
}

// ---------------------------------------------------------------------------
// Flash cross-attention v6 (R13/R16-verified, KVBLK=64, 4 waves).
// ---------------------------------------------------------------------------
__global__ __launch_bounds__(256, 1) void flash_cross(
    const __bf16* __restrict__ qgm, const __bf16* __restrict__ kg,
    const __bf16* __restrict__ vtg, __bf16* __restrict__ Opart,
    float* __restrict__ ml)
{
  extern __shared__ __bf16 smem[];
  __bf16* Ks = smem;            // [64][256] perm1-swizzled 16B chunks
  __bf16* Vt = smem + 64*256;   // [256][64] perm1-swizzled 16B chunks

  const int bid = blockIdx.x;
  const int xcd = bid & 7;
  const int grp = bid >> 3;
  const int qt  = grp & 7;
  const int pp  = xcd + 8*(grp >> 3);
  const int b   = pp >> 3;
  const int sl  = pp & 7;

  const int tid  = threadIdx.x;
  const int wid  = tid >> 6;
  const int lane = tid & 63;
  const int lq   = lane & 15;
  const int hi   = lane >> 4;
  const int lk8  = hi << 3;
  const int rb   = hi << 2;
  const int p1l  = perm1(lq & 7);

  const int q0 = b*1024 + qt*128 + wid*32;
  bf16x8 qf[2][8];
  #pragma unroll
  for (int g=0; g<2; g++)
    #pragma unroll
    for (int ks=0; ks<8; ks++)
      qf[g][ks] = *(const bf16x8*)&qgm[(size_t)(q0 + g*16 + lq)*256 + ks*32 + lk8];

  const f32x4 Z = {0.f, 0.f, 0.f, 0.f};
  float m[2] = {-1e30f, -1e30f};
  float l[2] = {0.f, 0.f};
  f32x4 o[2][16];
  #pragma unroll
  for (int g=0; g<2; g++)
    #pragma unroll
    for (int nf=0; nf<16; nf++) o[g][nf] = Z;

  const int srow = tid >> 2;
  const int c4   = tid & 3;
  const int p1s  = perm1(srow & 7);

  for (int it=0; it<8; ++it){
    const int key0 = sl*512 + it*64;
    __syncthreads();
    {
      const __bf16* kb = &kg[(size_t)(b*4096 + key0 + srow)*256];
      #pragma unroll
      for (int j=0;j<8;j++){
        const int ch = c4 + j*4;
        *(bf16x8*)&Ks[srow*256 + ((ch ^ p1s)<<3)] = *(const bf16x8*)(kb + ch*8);
      }
    }
    {
      #pragma unroll
      for (int ps=0; ps<4; ps++){
        const int d = srow + ps*64;
        const __bf16* vb = &vtg[(size_t)(b*256 + d)*4096 + key0];
        #pragma unroll
        for (int s2=0;s2<2;s2++){
          const int ch = c4 + s2*4;
          *(bf16x8*)&Vt[d*64 + ((ch ^ p1s)<<3)] = *(const bf16x8*)(vb + ch*8);
        }
      }
    }
    __syncthreads();
    f32x4 s4[2][4];
    #pragma unroll
    for (int g=0; g<2; g++)
      #pragma unroll
      for (int kt=0;kt<4;kt++) s4[g][kt] = Z;
    #pragma unroll
    for (int ks=0; ks<8; ks++){
      #pragma unroll
      for (int kt=0; kt<4; kt++){
        const bf16x8 kf = *(const bf16x8*)&Ks[(kt*16+lq)*256 + (((ks*4+hi) ^ p1l)<<3)];
        s4[0][kt] = MFMA16(kf, qf[0][ks], s4[0][kt]);
        s4[1][kt] = MFMA16(kf, qf[1][ks], s4[1][kt]);
      }
    }
    float pm[2];
    #pragma unroll
    for (int g=0; g<2; g++){
      float v = s4[g][0][0];
      #pragma unroll
      for (int kt=0;kt<4;kt++)
        #pragma unroll
        for (int r=0;r<4;r++) v = fmaxf(v, s4[g][kt][r]);
      v = fmaxf(v, __shfl_xor(v, 16));
      v = fmaxf(v, __shfl_xor(v, 32));
      pm[g] = v;
    }
    const bool need = (pm[0] > m[0] + 8.f) || (pm[1] > m[1] + 8.f);
    if (__any(need)){
      #pragma unroll
      for (int g=0; g<2; g++){
        const float mn = fmaxf(m[g], pm[g]);
        const float alpha = __expf(m[g] - mn);
        #pragma unroll
        for (int nf=0;nf<16;nf++){
          o[g][nf][0]*=alpha; o[g][nf][1]*=alpha;
          o[g][nf][2]*=alpha; o[g][nf][3]*=alpha;
        }
        l[g] *= alpha;
        m[g] = mn;
      }
    }
    bf16x8 pf[2][2];
    #pragma unroll
    for (int g=0; g<2; g++){
      float p[4][4];
      float rs = 0.f;
      #pragma unroll
      for (int kt=0;kt<4;kt++)
        #pragma unroll
        for (int r=0;r<4;r++){ p[kt][r] = __expf(s4[g][kt][r] - m[g]); rs += p[kt][r]; }
      rs += __shfl_xor(rs, 16);
      rs += __shfl_xor(rs, 32);
      l[g] += rs;
      unsigned pk0[4], pk1[4];
      #pragma unroll
      for (int kt=0;kt<4;kt++){
        pk0[kt] = pack2bf(p[kt][0], p[kt][1]);
        pk1[kt] = pack2bf(p[kt][2], p[kt][3]);
      }
      const int srcA = ((hi&1)<<5) + lq;
      const int srcB = srcA + 16;
      const bool ksel = hi >= 2;
      #pragma unroll
      for (int ks2=0; ks2<2; ks2++){
        const unsigned a0 = (unsigned)__shfl((int)pk0[2*ks2],   srcA);
        const unsigned a1 = (unsigned)__shfl((int)pk0[2*ks2+1], srcA);
        const unsigned b0 = (unsigned)__shfl((int)pk1[2*ks2],   srcA);
        const unsigned b1 = (unsigned)__shfl((int)pk1[2*ks2+1], srcA);
        const unsigned c0 = (unsigned)__shfl((int)pk0[2*ks2],   srcB);
        const unsigned c1 = (unsigned)__shfl((int)pk0[2*ks2+1], srcB);
        const unsigned d0 = (unsigned)__shfl((int)pk1[2*ks2],   srcB);
        const unsigned d1 = (unsigned)__shfl((int)pk1[2*ks2+1], srcB);
        union { unsigned u[4]; bf16x8 v; } uu;
        uu.u[0] = ksel ? a1 : a0;
        uu.u[1] = ksel ? b1 : b0;
        uu.u[2] = ksel ? c1 : c0;
        uu.u[3] = ksel ? d1 : d0;
        pf[g][ks2] = uu.v;
      }
    }
    #pragma unroll
    for (int nf=0; nf<16; nf++){
      #pragma unroll
      for (int ks2=0; ks2<2; ks2++){
        const bf16x8 af = *(const bf16x8*)&Vt[(nf*16+lq)*64 + (((ks2*4+hi) ^ p1l)<<3)];
        o[0][nf] = MFMA16(af, pf[0][ks2], o[0][nf]);
        o[1][nf] = MFMA16(af, pf[1][ks2], o[1][nf]);
      }
    }
  }
  #pragma unroll
  for (int g=0; g<2; g++){
    const int row = q0 + g*16 + lq;
    if (hi == 0){
      ml[(size_t)(sl*8192 + row)*2 + 0] = m[g];
      ml[(size_t)(sl*8192 + row)*2 + 1] = l[g];
    }
    #pragma unroll
    for (int nf=0; nf<16; nf++){
      bf16x4 hv;
      #pragma unroll
      for (int r=0;r<4;r++) hv[r] = (__bf16)o[g][nf][r];
      *(bf16x4*)&Opart[(size_t)(sl*8192 + row)*256 + nf*16 + rb] = hv;
    }
  }
}

// ---------------------------------------------------------------------------
__global__ __launch_bounds__(256) void combine_kernel(const __bf16* __restrict__ Opart,
                                                      const float* __restrict__ ml,
                                                      __bf16* __restrict__ out)
{
  const int row = blockIdx.x;
  const int d = threadIdx.x;
  float mm[8], ll[8];
  #pragma unroll
  for (int s=0;s<8;s++){
    mm[s] = ml[(size_t)(s*8192+row)*2 + 0];
    ll[s] = ml[(size_t)(s*8192+row)*2 + 1];
  }
  float M = mm[0];
  #pragma unroll
  for (int s=1;s<8;s++) M = fmaxf(M, mm[s]);
  float L = 0.f, acc = 0.f;
  #pragma unroll
  for (int s=0;s<8;s++){
    const float e = __expf(mm[s]-M);
    L   += ll[s]*e;
    acc += e * (float)Opart[(size_t)(s*8192+row)*256 + d];
  }
  out[(size_t)row*256 + d] = (__bf16)(acc / L);
}

// ---------------------------------------------------------------------------
extern "C" void kernel_launch(void* const* d_in, const int* in_sizes, int n_in,
                              void* d_out, int out_size, void* d_ws, size_t ws_size,
                              hipStream_t stream)
{
  (void)in_sizes; (void)n_in; (void)out_size; (void)ws_size;
  const float* tgt        = (const float*)d_in[0];
  const float* srcs       = (const float*)d_in[2];
  const float* posemb     = (const float*)d_in[3];
  const float* in_proj_w  = (const float*)d_in[4];
  const float* in_proj_b  = (const float*)d_in[5];
  const float* out_proj_w = (const float*)d_in[6];
  const float* out_proj_b = (const float*)d_in[7];
  const float* lin_q_w    = (const float*)d_in[8];
  const float* lin_q_b    = (const float*)d_in[9];
  const float* lin_k_w    = (const float*)d_in[10];
  const float* lin_k_b    = (const float*)d_in[11];
  const float* lin_v_w    = (const float*)d_in[12];
  const float* lin_v_b    = (const float*)d_in[13];
  const float* lin_o_w    = (const float*)d_in[14];
  const float* lin_o_b    = (const float*)d_in[15];
  const float* norm1_g    = (const float*)d_in[16];
  const float* norm1_b    = (const float*)d_in[17];
  const float* norm2_g    = (const float*)d_in[18];
  const float* norm2_b    = (const float*)d_in[19];
  const float* ffn_w1     = (const float*)d_in[20];
  const float* ffn_b1     = (const float*)d_in[21];
  const float* ffn_w2     = (const float*)d_in[22];
  const float* ffn_b2     = (const float*)d_in[23];
  const float* ffn_norm_g = (const float*)d_in[24];
  const float* ffn_norm_b = (const float*)d_in[25];
  float* out = (float*)d_out;

  char* w = (char*)d_ws;
  const size_t MB = (size_t)1 << 20;
  // Region plan (R13-audited):
  float*  tgt1    = (float*)(w + 0);
  __bf16* qk_s    = (__bf16*)(w + 8*MB);
  __bf16* query_b = (__bf16*)(w + 8*MB);
  __bf16* tgt1b   = (__bf16*)(w + 12*MB);
  __bf16* attn2   = (__bf16*)(w + 12*MB);
  __bf16* v_t     = (__bf16*)(w + 16*MB);
  __bf16* key_b   = (__bf16*)(w + 16*MB);
  float*  t2proj  = (float*)(w + 16*MB);
  __bf16* sa_b    = (__bf16*)(w + 20*MB);
  float*  saproj  = (float*)(w + 24*MB);
  float*  tgt3    = (float*)(w + 24*MB);
  __bf16* val_t   = (__bf16*)(w + 32*MB);
  __bf16* ffn_h   = (__bf16*)(w + 32*MB);
  __bf16* Opart   = (__bf16*)(w + 48*MB);
  float*  ffn_out = (float*)(w + 48*MB);
  __bf16* tgt3b   = (__bf16*)(w + 56*MB);
  float*  ml      = (float*)(w + 80*MB);
  __bf16* wb      = (__bf16*)(w + 81*MB);

  __bf16* wb_inproj = wb;
  __bf16* wb_outp   = wb + 196608;
  __bf16* wb_q      = wb + 262144;
  __bf16* wb_k      = wb + 327680;
  __bf16* wb_v      = wb + 393216;
  __bf16* wb_o      = wb + 458752;
  __bf16* wb_ff1    = wb + 524288;
  __bf16* wb_ff2    = wb + 786432;

  // 0: one-shot weight conversion
  cvt_weights<<<1024,256,0,stream>>>(in_proj_w, out_proj_w, lin_q_w, lin_k_w,
      lin_v_w, lin_o_w, ffn_w1, ffn_w2, wb);

  // ---- Stage A: self-attention ----
  gemm_bt<64,false,1,1,1><<<dim3(128,8),256,0,stream>>>(tgt, posemb,
      wb_inproj, in_proj_b, qk_s, 8192,512,256, 512,0, 1.f);
  gemm_bt<64,false,2,0,1><<<dim3(128,4),256,0,stream>>>(tgt, nullptr,
      wb_inproj + (size_t)512*256, in_proj_b + 512, v_t, 8192,256,256, 256,0, 1.f);
  flash_self<<<dim3(16,64),256,0,stream>>>(qk_s, v_t, sa_b);
  gemm_bt<64,false,0,2,1><<<dim3(128,4),256,0,stream>>>(sa_b, nullptr,
      wb_outp, out_proj_b, saproj, 8192,256,256, 256,0, 1.f);
  ln_kernel<<<2048,256,0,stream>>>(tgt, saproj, norm2_g, norm2_b, tgt1, tgt1b);

  // ---- Stage B: cross-attention ----
  gemm_bt<64,false,1,2,1><<<dim3(128,4),256,0,stream>>>(tgt1b, nullptr,
      wb_q, lin_q_b, query_b, 8192,256,256, 256,0, 1.f);
  gemm_srcs_kv<<<256,256,(128+64)*264*2,stream>>>(srcs,
      wb_k, lin_k_b, wb_v, lin_v_b, key_b, val_t);
  flash_cross<<<512,256,65536,stream>>>(query_b, key_b, val_t, Opart, ml);
  combine_kernel<<<8192,256,0,stream>>>(Opart, ml, attn2);
  gemm_bt<64,false,0,2,1><<<dim3(128,4),256,0,stream>>>(attn2, nullptr,
      wb_o, lin_o_b, t2proj, 8192,256,256, 256,0, 1.f);
  ln_kernel<<<2048,256,0,stream>>>(tgt1, t2proj, norm1_g, norm1_b, tgt3, tgt3b);

  // ---- Stage C: FFN ----
  gemm_bt<128,true,1,2,1><<<dim3(64,16),256,0,stream>>>(tgt3b, nullptr,
      wb_ff1, ffn_b1, ffn_h, 8192,1024,256, 1024,0, 1.f);
  gemm_bt<64,false,0,2,1><<<dim3(128,4),256,0,stream>>>(ffn_h, nullptr,
      wb_ff2, ffn_b2, ffn_out, 8192,256,1024, 256,0, 1.f);
  ln_kernel<<<2048,256,0,stream>>>(tgt3, ffn_out, ffn_norm_g, ffn_norm_b, out, nullptr);
}

// Round 19
// 278.785 us; speedup vs baseline: 1.0322x; 1.0068x over previous
//
#include <hip/hip_runtime.h>
#include <hip/hip_bf16.h>
#include <math.h>

typedef __attribute__((ext_vector_type(8))) __bf16 bf16x8;
typedef __attribute__((ext_vector_type(4))) __bf16 bf16x4;
typedef __attribute__((ext_vector_type(2))) __bf16 bf16x2;
typedef __attribute__((ext_vector_type(4))) float  f32x4;

#define MFMA16(a,b,c) __builtin_amdgcn_mfma_f32_16x16x32_bf16((a),(b),(c),0,0,0)

__device__ __forceinline__ unsigned pack2bf(float a, float b){
  bf16x2 t; t[0] = (__bf16)a; t[1] = (__bf16)b;
  return __builtin_bit_cast(unsigned, t);
}
__device__ __forceinline__ int perm1(int r){ return ((r<<2)|(r>>1)) & 7; }

__device__ __forceinline__ bf16x8 cvt8(const float4& a, const float4& b){
  bf16x8 h;
  h[0]=(__bf16)a.x; h[1]=(__bf16)a.y; h[2]=(__bf16)a.z; h[3]=(__bf16)a.w;
  h[4]=(__bf16)b.x; h[5]=(__bf16)b.y; h[6]=(__bf16)b.z; h[7]=(__bf16)b.w;
  return h;
}

// ---------------------------------------------------------------------------
// One-shot f32->bf16 weight conversion (verified R13).
// ---------------------------------------------------------------------------
__global__ __launch_bounds__(256) void cvt_weights(
    const float* __restrict__ w0, const float* __restrict__ w1,
    const float* __restrict__ w2, const float* __restrict__ w3,
    const float* __restrict__ w4, const float* __restrict__ w5,
    const float* __restrict__ w6, const float* __restrict__ w7,
    __bf16* __restrict__ dst)
{
  const int gid = blockIdx.x*256 + threadIdx.x;
  const float* src; int base, loc;
  if      (gid <  49152){ src = w0; base = 0;      loc = gid; }
  else if (gid <  65536){ src = w1; base = 196608; loc = gid -  49152; }
  else if (gid <  81920){ src = w2; base = 262144; loc = gid -  65536; }
  else if (gid <  98304){ src = w3; base = 327680; loc = gid -  81920; }
  else if (gid < 114688){ src = w4; base = 393216; loc = gid -  98304; }
  else if (gid < 131072){ src = w5; base = 458752; loc = gid - 114688; }
  else if (gid < 196608){ src = w6; base = 524288; loc = gid - 131072; }
  else                  { src = w7; base = 786432; loc = gid - 196608; }
  const float4 v = *(const float4*)&src[(size_t)loc*4];
  bf16x4 h; h[0]=(__bf16)v.x; h[1]=(__bf16)v.y; h[2]=(__bf16)v.z; h[3]=(__bf16)v.w;
  *(bf16x4*)&dst[(size_t)base + (size_t)loc*4] = h;
}

// ---------------------------------------------------------------------------
// Generic GEMM (verified R13).
// ---------------------------------------------------------------------------
template<int BM, bool RELU, int OUTMODE, int AMODE, int BMODE>
__global__ __launch_bounds__(256) void gemm_bt(
    const void* __restrict__ Av, const float* __restrict__ A2,
    const void* __restrict__ Wv,
    const float* __restrict__ bias, void* __restrict__ Cv,
    int M, int N, int K, int ldc, int coff, float oscale)
{
  constexpr int MT = BM/32;
  constexpr int PASSES = BM/64;
  __shared__ __align__(16) __bf16 As[BM][72];
  __shared__ __align__(16) __bf16 Bs[64][72];

  const int tid  = threadIdx.x;
  const int wid  = tid >> 6;
  const int lane = tid & 63;
  const int wr   = wid >> 1;
  const int wc   = wid & 1;
  const int lq   = lane & 15;
  const int lk8  = (lane >> 4) << 3;
  const int rb   = (lane >> 4) << 2;

  const int m0 = blockIdx.x * BM;
  const int n0 = blockIdx.y * 64;

  const int sr = tid >> 2;
  const int sc = (tid & 3) << 4;

  f32x4 acc[MT][2];
  #pragma unroll
  for (int i=0;i<MT;i++)
    #pragma unroll
    for (int j=0;j<2;j++) acc[i][j] = f32x4{0.f,0.f,0.f,0.f};

  for (int k0=0; k0<K; k0+=64){
    __syncthreads();
    #pragma unroll
    for (int p=0;p<PASSES;p++){
      const int row = sr + p*64;
      if (AMODE == 2){
        const __bf16* ap = (const __bf16*)Av + (size_t)(m0+row)*K + k0 + sc;
        *(bf16x8*)&As[row][sc]   = *(const bf16x8*)(ap);
        *(bf16x8*)&As[row][sc+8] = *(const bf16x8*)(ap + 8);
      } else {
        const float* ap = (const float*)Av + (size_t)(m0+row)*K + k0 + sc;
        float4 a0 = *(const float4*)(ap);
        float4 a1 = *(const float4*)(ap+4);
        float4 a2 = *(const float4*)(ap+8);
        float4 a3 = *(const float4*)(ap+12);
        if (AMODE == 1){
          const float* bp = A2 + (size_t)(m0+row)*K + k0 + sc;
          const float4 b0 = *(const float4*)(bp);
          const float4 b1 = *(const float4*)(bp+4);
          const float4 b2 = *(const float4*)(bp+8);
          const float4 b3 = *(const float4*)(bp+12);
          a0.x+=b0.x; a0.y+=b0.y; a0.z+=b0.z; a0.w+=b0.w;
          a1.x+=b1.x; a1.y+=b1.y; a1.z+=b1.z; a1.w+=b1.w;
          a2.x+=b2.x; a2.y+=b2.y; a2.z+=b2.z; a2.w+=b2.w;
          a3.x+=b3.x; a3.y+=b3.y; a3.z+=b3.z; a3.w+=b3.w;
        }
        *(bf16x8*)&As[row][sc]   = cvt8(a0,a1);
        *(bf16x8*)&As[row][sc+8] = cvt8(a2,a3);
      }
    }
    if (BMODE == 1){
      const __bf16* wp = (const __bf16*)Wv + (size_t)(n0+sr)*K + k0 + sc;
      *(bf16x8*)&Bs[sr][sc]   = *(const bf16x8*)(wp);
      *(bf16x8*)&Bs[sr][sc+8] = *(const bf16x8*)(wp + 8);
    } else {
      const float* wp = (const float*)Wv + (size_t)(n0+sr)*K + k0 + sc;
      const float4 a0 = *(const float4*)(wp);
      const float4 a1 = *(const float4*)(wp+4);
      const float4 a2 = *(const float4*)(wp+8);
      const float4 a3 = *(const float4*)(wp+12);
      *(bf16x8*)&Bs[sr][sc]   = cvt8(a0,a1);
      *(bf16x8*)&Bs[sr][sc+8] = cvt8(a2,a3);
    }
    __syncthreads();
    #pragma unroll
    for (int ksub=0; ksub<2; ksub++){
      bf16x8 bfr[2];
      #pragma unroll
      for (int j=0;j<2;j++)
        bfr[j] = *(const bf16x8*)&Bs[wc*32 + j*16 + lq][ksub*32 + lk8];
      #pragma unroll
      for (int i=0;i<MT;i++){
        const bf16x8 af = *(const bf16x8*)&As[wr*(BM/2) + i*16 + lq][ksub*32 + lk8];
        acc[i][0] = MFMA16(af, bfr[0], acc[i][0]);
        acc[i][1] = MFMA16(af, bfr[1], acc[i][1]);
      }
    }
  }

  #pragma unroll
  for (int i=0;i<MT;i++)
    #pragma unroll
    for (int j=0;j<2;j++){
      const int coln = n0 + wc*32 + j*16 + lq;
      const float bv = bias ? bias[coln] : 0.f;
      if (OUTMODE == 2){
        const int rowm0 = m0 + wr*(BM/2) + i*16 + rb;
        bf16x4 hv;
        #pragma unroll
        for (int r=0;r<4;r++){
          float vv = (acc[i][j][r] + bv) * oscale;
          if (RELU) vv = fmaxf(vv, 0.f);
          hv[r] = (__bf16)vv;
        }
        *(bf16x4*)&((__bf16*)Cv)[((size_t)((rowm0>>10)*256) + coln)*1024 + (rowm0&1023)] = hv;
      } else {
        #pragma unroll
        for (int r=0;r<4;r++){
          const int rowm = m0 + wr*(BM/2) + i*16 + rb + r;
          float vv = (acc[i][j][r] + bv) * oscale;
          if (RELU) vv = fmaxf(vv, 0.f);
          const size_t idx = (size_t)rowm*ldc + coff + coln;
          if (OUTMODE == 1) ((__bf16*)Cv)[idx] = (__bf16)vv;
          else              ((float*)Cv)[idx]  = vv;
        }
      }
    }
}

// ---------------------------------------------------------------------------
// Fused K/V projection from srcs (verified R11/R13).
// ---------------------------------------------------------------------------
__global__ __launch_bounds__(256) void gemm_srcs_kv(
    const float* __restrict__ S,
    const __bf16* __restrict__ Wk, const float* __restrict__ bk,
    const __bf16* __restrict__ Wv, const float* __restrict__ bv,
    __bf16* __restrict__ Kout, __bf16* __restrict__ Vt)
{
  extern __shared__ __bf16 lds[];
  __bf16* As = lds;              // [128][264]
  __bf16* Bs = lds + 128*264;    // [64][264]

  const int tid  = threadIdx.x;
  const int wid  = tid >> 6;
  const int lane = tid & 63;
  const int wr   = wid >> 1;
  const int wc   = wid & 1;
  const int lq   = lane & 15;
  const int lk8  = (lane >> 4) << 3;
  const int rb   = (lane >> 4) << 2;

  const int m0 = blockIdx.x * 128;
  const int bb = m0 >> 12;
  const int p0 = m0 & 4095;

  const int cA = tid & 31;
  const int qA = tid >> 5;
  for (int k0=0; k0<256; k0+=32){
    const float* sbase = &S[((size_t)bb*256 + k0 + cA)*4096 + p0];
    #pragma unroll
    for (int ps=0; ps<4; ps++){
      const int p = ps*32 + qA*4;
      const float4 f4 = *(const float4*)(sbase + p);
      As[(p+0)*264 + k0 + cA] = (__bf16)f4.x;
      As[(p+1)*264 + k0 + cA] = (__bf16)f4.y;
      As[(p+2)*264 + k0 + cA] = (__bf16)f4.z;
      As[(p+3)*264 + k0 + cA] = (__bf16)f4.w;
    }
  }

  const int sr  = tid >> 2;
  const int scb = (tid & 3) * 64;

  for (int half=0; half<2; half++){
    const __bf16* W   = half ? Wv : Wk;
    const float* bias = half ? bv : bk;
    for (int nt=0; nt<4; nt++){
      const int n0 = nt*64;
      __syncthreads();
      {
        const __bf16* wp = W + (size_t)(n0+sr)*256 + scb;
        #pragma unroll
        for (int j=0;j<4;j++){
          *(bf16x8*)&Bs[sr*264 + scb + j*16]     = *(const bf16x8*)(wp + j*16);
          *(bf16x8*)&Bs[sr*264 + scb + j*16 + 8] = *(const bf16x8*)(wp + j*16 + 8);
        }
      }
      __syncthreads();
      f32x4 acc[4][2];
      #pragma unroll
      for (int i=0;i<4;i++)
        #pragma unroll
        for (int j=0;j<2;j++) acc[i][j] = f32x4{0.f,0.f,0.f,0.f};
      #pragma unroll
      for (int k0=0; k0<256; k0+=32){
        bf16x8 bfr[2];
        #pragma unroll
        for (int j=0;j<2;j++)
          bfr[j] = *(const bf16x8*)&Bs[(wc*32 + j*16 + lq)*264 + k0 + lk8];
        #pragma unroll
        for (int i=0;i<4;i++){
          const bf16x8 af = *(const bf16x8*)&As[(wr*64 + i*16 + lq)*264 + k0 + lk8];
          acc[i][0] = MFMA16(af, bfr[0], acc[i][0]);
          acc[i][1] = MFMA16(af, bfr[1], acc[i][1]);
        }
      }
      #pragma unroll
      for (int i=0;i<4;i++)
        #pragma unroll
        for (int j=0;j<2;j++){
          const int coln = n0 + wc*32 + j*16 + lq;
          const float bvv = bias[coln];
          if (half){
            bf16x4 hv;
            #pragma unroll
            for (int r=0;r<4;r++) hv[r] = (__bf16)(acc[i][j][r] + bvv);
            *(bf16x4*)&Vt[((size_t)bb*256 + coln)*4096 + p0 + wr*64 + i*16 + rb] = hv;
          } else {
            #pragma unroll
            for (int r=0;r<4;r++){
              const int rowm = m0 + wr*64 + i*16 + rb + r;
              Kout[(size_t)rowm*256 + coln] = (__bf16)(acc[i][j][r] + bvv);
            }
          }
        }
    }
  }
}

// ---------------------------------------------------------------------------
// LN: out = LN(res + x)*g + beta. res f32, x bf16 (projection output).
// ---------------------------------------------------------------------------
__global__ __launch_bounds__(256) void ln_kernel(const float* __restrict__ res,
                                                 const __bf16* __restrict__ x,
                                                 const float* __restrict__ g,
                                                 const float* __restrict__ beta,
                                                 float* __restrict__ out,
                                                 __bf16* __restrict__ outb)
{
  const int row  = blockIdx.x*4 + (threadIdx.x >> 6);
  const int lane = threadIdx.x & 63;
  const int c = lane*4;
  const float4 rv = *(const float4*)&res[(size_t)row*256 + c];
  const bf16x4 xv = *(const bf16x4*)&x[(size_t)row*256 + c];
  float v0=rv.x+(float)xv[0], v1=rv.y+(float)xv[1];
  float v2=rv.z+(float)xv[2], v3=rv.w+(float)xv[3];
  float s = v0+v1+v2+v3;
  #pragma unroll
  for (int off=1; off<64; off<<=1) s += __shfl_xor(s, off);
  const float mean = s * (1.f/256.f);
  const float d0=v0-mean, d1=v1-mean, d2=v2-mean, d3=v3-mean;
  float q = d0*d0 + d1*d1 + d2*d2 + d3*d3;
  #pragma unroll
  for (int off=1; off<64; off<<=1) q += __shfl_xor(q, off);
  const float rstd = rsqrtf(q*(1.f/256.f) + 1e-5f);
  const float4 gv = *(const float4*)&g[c];
  const float4 bv = *(const float4*)&beta[c];
  float4 ov;
  ov.x = d0*rstd*gv.x + bv.x;
  ov.y = d1*rstd*gv.y + bv.y;
  ov.z = d2*rstd*gv.z + bv.z;
  ov.w = d3*rstd*gv.w + bv.w;
  *(float4*)&out[(size_t)row*256 + c] = ov;
  if (outb){
    bf16x4 hv;
    hv[0]=(__bf16)ov.x; hv[1]=(__bf16)ov.y; hv[2]=(__bf16)ov.z; hv[3]=(__bf16)ov.w;
    *(bf16x4*)&outb[(size_t)row*256 + c] = hv;
  }
}

// ---------------------------------------------------------------------------
// Flash self-attention (verified R10-R13).
// ---------------------------------------------------------------------------
__global__ __launch_bounds__(256) void flash_self(
    const __bf16* __restrict__ qks, const __bf16* __restrict__ vts,
    __bf16* __restrict__ sab)
{
  const int qt = blockIdx.x;
  const int b  = blockIdx.y >> 3;
  const int h  = blockIdx.y & 7;
  const int tid  = threadIdx.x;
  const int wid  = tid >> 6;
  const int lane = tid & 63;
  const int lq   = lane & 15;
  const int hi   = lane >> 4;
  const int lk8  = hi << 3;
  const int rb   = hi << 2;
  const float SCALE = 0.17677669529663687f;

  const int qrow = b*1024 + qt*64 + wid*16 + lq;
  const bf16x8 qf = *(const bf16x8*)&qks[(size_t)qrow*512 + h*32 + lk8];

  const __bf16* kb0 = &qks[(size_t)(b*1024 + lq)*512 + 256 + h*32 + lk8];
  const __bf16* vb0 = &vts[(size_t)(b*256 + h*32 + lq)*1024 + lk8];

  const f32x4 Z = {0.f, 0.f, 0.f, 0.f};
  float m = -1e30f, l = 0.f;
  f32x4 o0 = Z, o1 = Z;

  for (int it=0; it<16; ++it){
    const int key0 = it*64;
    f32x4 s4[4];
    #pragma unroll
    for (int kt=0;kt<4;kt++){
      const bf16x8 kf = *(const bf16x8*)(kb0 + (size_t)(key0 + kt*16)*512);
      s4[kt] = MFMA16(kf, qf, Z);
      #pragma unroll
      for (int r=0;r<4;r++) s4[kt][r] *= SCALE;
    }
    float pm = s4[0][0];
    #pragma unroll
    for (int kt=0;kt<4;kt++)
      #pragma unroll
      for (int r=0;r<4;r++) pm = fmaxf(pm, s4[kt][r]);
    pm = fmaxf(pm, __shfl_xor(pm,16));
    pm = fmaxf(pm, __shfl_xor(pm,32));
    if (!__all(pm <= m + 8.f)){
      const float mn = fmaxf(m, pm);
      const float alpha = __expf(m - mn);
      o0[0]*=alpha; o0[1]*=alpha; o0[2]*=alpha; o0[3]*=alpha;
      o1[0]*=alpha; o1[1]*=alpha; o1[2]*=alpha; o1[3]*=alpha;
      l *= alpha;
      m = mn;
    }
    float p[4][4]; float rs = 0.f;
    #pragma unroll
    for (int kt=0;kt<4;kt++)
      #pragma unroll
      for (int r=0;r<4;r++){ p[kt][r] = __expf(s4[kt][r]-m); rs += p[kt][r]; }
    rs += __shfl_xor(rs,16);
    rs += __shfl_xor(rs,32);
    l += rs;
    unsigned pk0[4], pk1[4];
    #pragma unroll
    for (int kt=0;kt<4;kt++){
      pk0[kt] = pack2bf(p[kt][0], p[kt][1]);
      pk1[kt] = pack2bf(p[kt][2], p[kt][3]);
    }
    const int srcA = ((hi&1)<<5) + lq;
    const int srcB = srcA + 16;
    const bool ksel = hi >= 2;
    bf16x8 pf[2];
    #pragma unroll
    for (int ks2=0; ks2<2; ks2++){
      const unsigned a0 = (unsigned)__shfl((int)pk0[2*ks2],   srcA);
      const unsigned a1 = (unsigned)__shfl((int)pk0[2*ks2+1], srcA);
      const unsigned b0 = (unsigned)__shfl((int)pk1[2*ks2],   srcA);
      const unsigned b1 = (unsigned)__shfl((int)pk1[2*ks2+1], srcA);
      const unsigned c0 = (unsigned)__shfl((int)pk0[2*ks2],   srcB);
      const unsigned c1 = (unsigned)__shfl((int)pk0[2*ks2+1], srcB);
      const unsigned d0 = (unsigned)__shfl((int)pk1[2*ks2],   srcB);
      const unsigned d1 = (unsigned)__shfl((int)pk1[2*ks2+1], srcB);
      union { unsigned u[4]; bf16x8 v; } uu;
      uu.u[0] = ksel ? a1 : a0;
      uu.u[1] = ksel ? b1 : b0;
      uu.u[2] = ksel ? c1 : c0;
      uu.u[3] = ksel ? d1 : d0;
      pf[ks2] = uu.v;
    }
    #pragma unroll
    for (int ks2=0; ks2<2; ks2++){
      const bf16x8 vf0 = *(const bf16x8*)(vb0 + key0 + ks2*32);
      const bf16x8 vf1 = *(const bf16x8*)(vb0 + (size_t)16*1024 + key0 + ks2*32);
      o0 = MFMA16(vf0, pf[ks2], o0);
      o1 = MFMA16(vf1, pf[ks2], o1);
    }
  }
  const float inv = 1.f / l;
  bf16x4 w0, w1;
  #pragma unroll
  for (int r=0;r<4;r++){ w0[r] = (__bf16)(o0[r]*inv); w1[r] = (__bf16)(o1[r]*inv); }
  *(bf16x4*)&sab[(size_t)qrow*256 + h*32 + rb]      = w0;
  *(bf16x4*)&sab[(size_t)qrow*256 + h*32 + 16 + rb] = w1;
}

// ---------------------------------------------------------------------------
// Flash cross-attention v6 (R13/R16/R18-verified, KVBLK=64, 4 waves).
// ---------------------------------------------------------------------------
__global__ __launch_bounds__(256, 1) void flash_cross(
    const __bf16* __restrict__ qgm, const __bf16* __restrict__ kg,
    const __bf16* __restrict__ vtg, __bf16* __restrict__ Opart,
    float* __restrict__ ml)
{
  extern __shared__ __bf16 smem[];
  __bf16* Ks = smem;            // [64][256] perm1-swizzled 16B chunks
  __bf16* Vt = smem + 64*256;   // [256][64] perm1-swizzled 16B chunks

  const int bid = blockIdx.x;
  const int xcd = bid & 7;
  const int grp = bid >> 3;
  const int qt  = grp & 7;
  const int pp  = xcd + 8*(grp >> 3);
  const int b   = pp >> 3;
  const int sl  = pp & 7;

  const int tid  = threadIdx.x;
  const int wid  = tid >> 6;
  const int lane = tid & 63;
  const int lq   = lane & 15;
  const int hi   = lane >> 4;
  const int lk8  = hi << 3;
  const int rb   = hi << 2;
  const int p1l  = perm1(lq & 7);

  const int q0 = b*1024 + qt*128 + wid*32;
  bf16x8 qf[2][8];
  #pragma unroll
  for (int g=0; g<2; g++)
    #pragma unroll
    for (int ks=0; ks<8; ks++)
      qf[g][ks] = *(const bf16x8*)&qgm[(size_t)(q0 + g*16 + lq)*256 + ks*32 + lk8];

  const f32x4 Z = {0.f, 0.f, 0.f, 0.f};
  float m[2] = {-1e30f, -1e30f};
  float l[2] = {0.f, 0.f};
  f32x4 o[2][16];
  #pragma unroll
  for (int g=0; g<2; g++)
    #pragma unroll
    for (int nf=0; nf<16; nf++) o[g][nf] = Z;

  const int srow = tid >> 2;
  const int c4   = tid & 3;
  const int p1s  = perm1(srow & 7);

  for (int it=0; it<8; ++it){
    const int key0 = sl*512 + it*64;
    __syncthreads();
    {
      const __bf16* kb = &kg[(size_t)(b*4096 + key0 + srow)*256];
      #pragma unroll
      for (int j=0;j<8;j++){
        const int ch = c4 + j*4;
        *(bf16x8*)&Ks[srow*256 + ((ch ^ p1s)<<3)] = *(const bf16x8*)(kb + ch*8);
      }
    }
    {
      #pragma unroll
      for (int ps=0; ps<4; ps++){
        const int d = srow + ps*64;
        const __bf16* vb = &vtg[(size_t)(b*256 + d)*4096 + key0];
        #pragma unroll
        for (int s2=0;s2<2;s2++){
          const int ch = c4 + s2*4;
          *(bf16x8*)&Vt[d*64 + ((ch ^ p1s)<<3)] = *(const bf16x8*)(vb + ch*8);
        }
      }
    }
    __syncthreads();
    f32x4 s4[2][4];
    #pragma unroll
    for (int g=0; g<2; g++)
      #pragma unroll
      for (int kt=0;kt<4;kt++) s4[g][kt] = Z;
    #pragma unroll
    for (int ks=0; ks<8; ks++){
      #pragma unroll
      for (int kt=0; kt<4; kt++){
        const bf16x8 kf = *(const bf16x8*)&Ks[(kt*16+lq)*256 + (((ks*4+hi) ^ p1l)<<3)];
        s4[0][kt] = MFMA16(kf, qf[0][ks], s4[0][kt]);
        s4[1][kt] = MFMA16(kf, qf[1][ks], s4[1][kt]);
      }
    }
    float pm[2];
    #pragma unroll
    for (int g=0; g<2; g++){
      float v = s4[g][0][0];
      #pragma unroll
      for (int kt=0;kt<4;kt++)
        #pragma unroll
        for (int r=0;r<4;r++) v = fmaxf(v, s4[g][kt][r]);
      v = fmaxf(v, __shfl_xor(v, 16));
      v = fmaxf(v, __shfl_xor(v, 32));
      pm[g] = v;
    }
    const bool need = (pm[0] > m[0] + 8.f) || (pm[1] > m[1] + 8.f);
    if (__any(need)){
      #pragma unroll
      for (int g=0; g<2; g++){
        const float mn = fmaxf(m[g], pm[g]);
        const float alpha = __expf(m[g] - mn);
        #pragma unroll
        for (int nf=0;nf<16;nf++){
          o[g][nf][0]*=alpha; o[g][nf][1]*=alpha;
          o[g][nf][2]*=alpha; o[g][nf][3]*=alpha;
        }
        l[g] *= alpha;
        m[g] = mn;
      }
    }
    bf16x8 pf[2][2];
    #pragma unroll
    for (int g=0; g<2; g++){
      float p[4][4];
      float rs = 0.f;
      #pragma unroll
      for (int kt=0;kt<4;kt++)
        #pragma unroll
        for (int r=0;r<4;r++){ p[kt][r] = __expf(s4[g][kt][r] - m[g]); rs += p[kt][r]; }
      rs += __shfl_xor(rs, 16);
      rs += __shfl_xor(rs, 32);
      l[g] += rs;
      unsigned pk0[4], pk1[4];
      #pragma unroll
      for (int kt=0;kt<4;kt++){
        pk0[kt] = pack2bf(p[kt][0], p[kt][1]);
        pk1[kt] = pack2bf(p[kt][2], p[kt][3]);
      }
      const int srcA = ((hi&1)<<5) + lq;
      const int srcB = srcA + 16;
      const bool ksel = hi >= 2;
      #pragma unroll
      for (int ks2=0; ks2<2; ks2++){
        const unsigned a0 = (unsigned)__shfl((int)pk0[2*ks2],   srcA);
        const unsigned a1 = (unsigned)__shfl((int)pk0[2*ks2+1], srcA);
        const unsigned b0 = (unsigned)__shfl((int)pk1[2*ks2],   srcA);
        const unsigned b1 = (unsigned)__shfl((int)pk1[2*ks2+1], srcA);
        const unsigned c0 = (unsigned)__shfl((int)pk0[2*ks2],   srcB);
        const unsigned c1 = (unsigned)__shfl((int)pk0[2*ks2+1], srcB);
        const unsigned d0 = (unsigned)__shfl((int)pk1[2*ks2],   srcB);
        const unsigned d1 = (unsigned)__shfl((int)pk1[2*ks2+1], srcB);
        union { unsigned u[4]; bf16x8 v; } uu;
        uu.u[0] = ksel ? a1 : a0;
        uu.u[1] = ksel ? b1 : b0;
        uu.u[2] = ksel ? c1 : c0;
        uu.u[3] = ksel ? d1 : d0;
        pf[g][ks2] = uu.v;
      }
    }
    #pragma unroll
    for (int nf=0; nf<16; nf++){
      #pragma unroll
      for (int ks2=0; ks2<2; ks2++){
        const bf16x8 af = *(const bf16x8*)&Vt[(nf*16+lq)*64 + (((ks2*4+hi) ^ p1l)<<3)];
        o[0][nf] = MFMA16(af, pf[0][ks2], o[0][nf]);
        o[1][nf] = MFMA16(af, pf[1][ks2], o[1][nf]);
      }
    }
  }
  #pragma unroll
  for (int g=0; g<2; g++){
    const int row = q0 + g*16 + lq;
    if (hi == 0){
      ml[(size_t)(sl*8192 + row)*2 + 0] = m[g];
      ml[(size_t)(sl*8192 + row)*2 + 1] = l[g];
    }
    #pragma unroll
    for (int nf=0; nf<16; nf++){
      bf16x4 hv;
      #pragma unroll
      for (int r=0;r<4;r++) hv[r] = (__bf16)o[g][nf][r];
      *(bf16x4*)&Opart[(size_t)(sl*8192 + row)*256 + nf*16 + rb] = hv;
    }
  }
}

// ---------------------------------------------------------------------------
__global__ __launch_bounds__(256) void combine_kernel(const __bf16* __restrict__ Opart,
                                                      const float* __restrict__ ml,
                                                      __bf16* __restrict__ out)
{
  const int row = blockIdx.x;
  const int d = threadIdx.x;
  float mm[8], ll[8];
  #pragma unroll
  for (int s=0;s<8;s++){
    mm[s] = ml[(size_t)(s*8192+row)*2 + 0];
    ll[s] = ml[(size_t)(s*8192+row)*2 + 1];
  }
  float M = mm[0];
  #pragma unroll
  for (int s=1;s<8;s++) M = fmaxf(M, mm[s]);
  float L = 0.f, acc = 0.f;
  #pragma unroll
  for (int s=0;s<8;s++){
    const float e = __expf(mm[s]-M);
    L   += ll[s]*e;
    acc += e * (float)Opart[(size_t)(s*8192+row)*256 + d];
  }
  out[(size_t)row*256 + d] = (__bf16)(acc / L);
}

// ---------------------------------------------------------------------------
extern "C" void kernel_launch(void* const* d_in, const int* in_sizes, int n_in,
                              void* d_out, int out_size, void* d_ws, size_t ws_size,
                              hipStream_t stream)
{
  (void)in_sizes; (void)n_in; (void)out_size; (void)ws_size;
  const float* tgt        = (const float*)d_in[0];
  const float* srcs       = (const float*)d_in[2];
  const float* posemb     = (const float*)d_in[3];
  const float* in_proj_w  = (const float*)d_in[4];
  const float* in_proj_b  = (const float*)d_in[5];
  const float* out_proj_w = (const float*)d_in[6];
  const float* out_proj_b = (const float*)d_in[7];
  const float* lin_q_w    = (const float*)d_in[8];
  const float* lin_q_b    = (const float*)d_in[9];
  const float* lin_k_w    = (const float*)d_in[10];
  const float* lin_k_b    = (const float*)d_in[11];
  const float* lin_v_w    = (const float*)d_in[12];
  const float* lin_v_b    = (const float*)d_in[13];
  const float* lin_o_w    = (const float*)d_in[14];
  const float* lin_o_b    = (const float*)d_in[15];
  const float* norm1_g    = (const float*)d_in[16];
  const float* norm1_b    = (const float*)d_in[17];
  const float* norm2_g    = (const float*)d_in[18];
  const float* norm2_b    = (const float*)d_in[19];
  const float* ffn_w1     = (const float*)d_in[20];
  const float* ffn_b1     = (const float*)d_in[21];
  const float* ffn_w2     = (const float*)d_in[22];
  const float* ffn_b2     = (const float*)d_in[23];
  const float* ffn_norm_g = (const float*)d_in[24];
  const float* ffn_norm_b = (const float*)d_in[25];
  float* out = (float*)d_out;

  char* w = (char*)d_ws;
  const size_t MB = (size_t)1 << 20;
  // Region plan (R13-audited; saproj/t2proj/ffn_out now bf16, 4MB each):
  float*  tgt1    = (float*)(w + 0);
  __bf16* qk_s    = (__bf16*)(w + 8*MB);
  __bf16* query_b = (__bf16*)(w + 8*MB);
  __bf16* tgt1b   = (__bf16*)(w + 12*MB);
  __bf16* attn2   = (__bf16*)(w + 12*MB);
  __bf16* v_t     = (__bf16*)(w + 16*MB);
  __bf16* key_b   = (__bf16*)(w + 16*MB);
  __bf16* t2proj  = (__bf16*)(w + 16*MB);
  __bf16* sa_b    = (__bf16*)(w + 20*MB);
  __bf16* saproj  = (__bf16*)(w + 24*MB);
  float*  tgt3    = (float*)(w + 24*MB);
  __bf16* val_t   = (__bf16*)(w + 32*MB);
  __bf16* ffn_h   = (__bf16*)(w + 32*MB);
  __bf16* Opart   = (__bf16*)(w + 48*MB);
  __bf16* ffn_out = (__bf16*)(w + 48*MB);
  __bf16* tgt3b   = (__bf16*)(w + 56*MB);
  float*  ml      = (float*)(w + 80*MB);
  __bf16* wb      = (__bf16*)(w + 81*MB);

  __bf16* wb_inproj = wb;
  __bf16* wb_outp   = wb + 196608;
  __bf16* wb_q      = wb + 262144;
  __bf16* wb_k      = wb + 327680;
  __bf16* wb_v      = wb + 393216;
  __bf16* wb_o      = wb + 458752;
  __bf16* wb_ff1    = wb + 524288;
  __bf16* wb_ff2    = wb + 786432;

  // 0: one-shot weight conversion
  cvt_weights<<<1024,256,0,stream>>>(in_proj_w, out_proj_w, lin_q_w, lin_k_w,
      lin_v_w, lin_o_w, ffn_w1, ffn_w2, wb);

  // ---- Stage A: self-attention ----
  gemm_bt<64,false,1,1,1><<<dim3(128,8),256,0,stream>>>(tgt, posemb,
      wb_inproj, in_proj_b, qk_s, 8192,512,256, 512,0, 1.f);
  gemm_bt<64,false,2,0,1><<<dim3(128,4),256,0,stream>>>(tgt, nullptr,
      wb_inproj + (size_t)512*256, in_proj_b + 512, v_t, 8192,256,256, 256,0, 1.f);
  flash_self<<<dim3(16,64),256,0,stream>>>(qk_s, v_t, sa_b);
  gemm_bt<64,false,1,2,1><<<dim3(128,4),256,0,stream>>>(sa_b, nullptr,
      wb_outp, out_proj_b, saproj, 8192,256,256, 256,0, 1.f);
  ln_kernel<<<2048,256,0,stream>>>(tgt, saproj, norm2_g, norm2_b, tgt1, tgt1b);

  // ---- Stage B: cross-attention ----
  gemm_bt<64,false,1,2,1><<<dim3(128,4),256,0,stream>>>(tgt1b, nullptr,
      wb_q, lin_q_b, query_b, 8192,256,256, 256,0, 1.f);
  gemm_srcs_kv<<<256,256,(128+64)*264*2,stream>>>(srcs,
      wb_k, lin_k_b, wb_v, lin_v_b, key_b, val_t);
  flash_cross<<<512,256,65536,stream>>>(query_b, key_b, val_t, Opart, ml);
  combine_kernel<<<8192,256,0,stream>>>(Opart, ml, attn2);
  gemm_bt<64,false,1,2,1><<<dim3(128,4),256,0,stream>>>(attn2, nullptr,
      wb_o, lin_o_b, t2proj, 8192,256,256, 256,0, 1.f);
  ln_kernel<<<2048,256,0,stream>>>(tgt1, t2proj, norm1_g, norm1_b, tgt3, tgt3b);

  // ---- Stage C: FFN ----
  gemm_bt<128,true,1,2,1><<<dim3(64,16),256,0,stream>>>(tgt3b, nullptr,
      wb_ff1, ffn_b1, ffn_h, 8192,1024,256, 1024,0, 1.f);
  gemm_bt<64,false,1,2,1><<<dim3(128,4),256,0,stream>>>(ffn_h, nullptr,
      wb_ff2, ffn_b2, ffn_out, 8192,256,1024, 256,0, 1.f);
  ln_kernel<<<2048,256,0,stream>>>(tgt3, ffn_out, ffn_norm_g, ffn_norm_b, out, nullptr);
}

// Round 20
// 276.191 us; speedup vs baseline: 1.0419x; 1.0094x over previous
//
#include <hip/hip_runtime.h>
#include <hip/hip_bf16.h>
#include <math.h>

typedef __attribute__((ext_vector_type(8))) __bf16 bf16x8;
typedef __attribute__((ext_vector_type(4))) __bf16 bf16x4;
typedef __attribute__((ext_vector_type(2))) __bf16 bf16x2;
typedef __attribute__((ext_vector_type(4))) float  f32x4;

#define MFMA16(a,b,c) __builtin_amdgcn_mfma_f32_16x16x32_bf16((a),(b),(c),0,0,0)

__device__ __forceinline__ unsigned pack2bf(float a, float b){
  bf16x2 t; t[0] = (__bf16)a; t[1] = (__bf16)b;
  return __builtin_bit_cast(unsigned, t);
}
__device__ __forceinline__ int perm1(int r){ return ((r<<2)|(r>>1)) & 7; }

__device__ __forceinline__ bf16x8 cvt8(const float4& a, const float4& b){
  bf16x8 h;
  h[0]=(__bf16)a.x; h[1]=(__bf16)a.y; h[2]=(__bf16)a.z; h[3]=(__bf16)a.w;
  h[4]=(__bf16)b.x; h[5]=(__bf16)b.y; h[6]=(__bf16)b.z; h[7]=(__bf16)b.w;
  return h;
}

// ---------------------------------------------------------------------------
// One-shot f32->bf16 weight conversion (verified R13).
// ---------------------------------------------------------------------------
__global__ __launch_bounds__(256) void cvt_weights(
    const float* __restrict__ w0, const float* __restrict__ w1,
    const float* __restrict__ w2, const float* __restrict__ w3,
    const float* __restrict__ w4, const float* __restrict__ w5,
    const float* __restrict__ w6, const float* __restrict__ w7,
    __bf16* __restrict__ dst)
{
  const int gid = blockIdx.x*256 + threadIdx.x;
  const float* src; int base, loc;
  if      (gid <  49152){ src = w0; base = 0;      loc = gid; }
  else if (gid <  65536){ src = w1; base = 196608; loc = gid -  49152; }
  else if (gid <  81920){ src = w2; base = 262144; loc = gid -  65536; }
  else if (gid <  98304){ src = w3; base = 327680; loc = gid -  81920; }
  else if (gid < 114688){ src = w4; base = 393216; loc = gid -  98304; }
  else if (gid < 131072){ src = w5; base = 458752; loc = gid - 114688; }
  else if (gid < 196608){ src = w6; base = 524288; loc = gid - 131072; }
  else                  { src = w7; base = 786432; loc = gid - 196608; }
  const float4 v = *(const float4*)&src[(size_t)loc*4];
  bf16x4 h; h[0]=(__bf16)v.x; h[1]=(__bf16)v.y; h[2]=(__bf16)v.z; h[3]=(__bf16)v.w;
  *(bf16x4*)&dst[(size_t)base + (size_t)loc*4] = h;
}

// ---------------------------------------------------------------------------
// Generic GEMM (verified R13).
// ---------------------------------------------------------------------------
template<int BM, bool RELU, int OUTMODE, int AMODE, int BMODE>
__global__ __launch_bounds__(256) void gemm_bt(
    const void* __restrict__ Av, const float* __restrict__ A2,
    const void* __restrict__ Wv,
    const float* __restrict__ bias, void* __restrict__ Cv,
    int M, int N, int K, int ldc, int coff, float oscale)
{
  constexpr int MT = BM/32;
  constexpr int PASSES = BM/64;
  __shared__ __align__(16) __bf16 As[BM][72];
  __shared__ __align__(16) __bf16 Bs[64][72];

  const int tid  = threadIdx.x;
  const int wid  = tid >> 6;
  const int lane = tid & 63;
  const int wr   = wid >> 1;
  const int wc   = wid & 1;
  const int lq   = lane & 15;
  const int lk8  = (lane >> 4) << 3;
  const int rb   = (lane >> 4) << 2;

  const int m0 = blockIdx.x * BM;
  const int n0 = blockIdx.y * 64;

  const int sr = tid >> 2;
  const int sc = (tid & 3) << 4;

  f32x4 acc[MT][2];
  #pragma unroll
  for (int i=0;i<MT;i++)
    #pragma unroll
    for (int j=0;j<2;j++) acc[i][j] = f32x4{0.f,0.f,0.f,0.f};

  for (int k0=0; k0<K; k0+=64){
    __syncthreads();
    #pragma unroll
    for (int p=0;p<PASSES;p++){
      const int row = sr + p*64;
      if (AMODE == 2){
        const __bf16* ap = (const __bf16*)Av + (size_t)(m0+row)*K + k0 + sc;
        *(bf16x8*)&As[row][sc]   = *(const bf16x8*)(ap);
        *(bf16x8*)&As[row][sc+8] = *(const bf16x8*)(ap + 8);
      } else {
        const float* ap = (const float*)Av + (size_t)(m0+row)*K + k0 + sc;
        float4 a0 = *(const float4*)(ap);
        float4 a1 = *(const float4*)(ap+4);
        float4 a2 = *(const float4*)(ap+8);
        float4 a3 = *(const float4*)(ap+12);
        if (AMODE == 1){
          const float* bp = A2 + (size_t)(m0+row)*K + k0 + sc;
          const float4 b0 = *(const float4*)(bp);
          const float4 b1 = *(const float4*)(bp+4);
          const float4 b2 = *(const float4*)(bp+8);
          const float4 b3 = *(const float4*)(bp+12);
          a0.x+=b0.x; a0.y+=b0.y; a0.z+=b0.z; a0.w+=b0.w;
          a1.x+=b1.x; a1.y+=b1.y; a1.z+=b1.z; a1.w+=b1.w;
          a2.x+=b2.x; a2.y+=b2.y; a2.z+=b2.z; a2.w+=b2.w;
          a3.x+=b3.x; a3.y+=b3.y; a3.z+=b3.z; a3.w+=b3.w;
        }
        *(bf16x8*)&As[row][sc]   = cvt8(a0,a1);
        *(bf16x8*)&As[row][sc+8] = cvt8(a2,a3);
      }
    }
    if (BMODE == 1){
      const __bf16* wp = (const __bf16*)Wv + (size_t)(n0+sr)*K + k0 + sc;
      *(bf16x8*)&Bs[sr][sc]   = *(const bf16x8*)(wp);
      *(bf16x8*)&Bs[sr][sc+8] = *(const bf16x8*)(wp + 8);
    } else {
      const float* wp = (const float*)Wv + (size_t)(n0+sr)*K + k0 + sc;
      const float4 a0 = *(const float4*)(wp);
      const float4 a1 = *(const float4*)(wp+4);
      const float4 a2 = *(const float4*)(wp+8);
      const float4 a3 = *(const float4*)(wp+12);
      *(bf16x8*)&Bs[sr][sc]   = cvt8(a0,a1);
      *(bf16x8*)&Bs[sr][sc+8] = cvt8(a2,a3);
    }
    __syncthreads();
    #pragma unroll
    for (int ksub=0; ksub<2; ksub++){
      bf16x8 bfr[2];
      #pragma unroll
      for (int j=0;j<2;j++)
        bfr[j] = *(const bf16x8*)&Bs[wc*32 + j*16 + lq][ksub*32 + lk8];
      #pragma unroll
      for (int i=0;i<MT;i++){
        const bf16x8 af = *(const bf16x8*)&As[wr*(BM/2) + i*16 + lq][ksub*32 + lk8];
        acc[i][0] = MFMA16(af, bfr[0], acc[i][0]);
        acc[i][1] = MFMA16(af, bfr[1], acc[i][1]);
      }
    }
  }

  #pragma unroll
  for (int i=0;i<MT;i++)
    #pragma unroll
    for (int j=0;j<2;j++){
      const int coln = n0 + wc*32 + j*16 + lq;
      const float bv = bias ? bias[coln] : 0.f;
      if (OUTMODE == 2){
        const int rowm0 = m0 + wr*(BM/2) + i*16 + rb;
        bf16x4 hv;
        #pragma unroll
        for (int r=0;r<4;r++){
          float vv = (acc[i][j][r] + bv) * oscale;
          if (RELU) vv = fmaxf(vv, 0.f);
          hv[r] = (__bf16)vv;
        }
        *(bf16x4*)&((__bf16*)Cv)[((size_t)((rowm0>>10)*256) + coln)*1024 + (rowm0&1023)] = hv;
      } else {
        #pragma unroll
        for (int r=0;r<4;r++){
          const int rowm = m0 + wr*(BM/2) + i*16 + rb + r;
          float vv = (acc[i][j][r] + bv) * oscale;
          if (RELU) vv = fmaxf(vv, 0.f);
          const size_t idx = (size_t)rowm*ldc + coff + coln;
          if (OUTMODE == 1) ((__bf16*)Cv)[idx] = (__bf16)vv;
          else              ((float*)Cv)[idx]  = vv;
        }
      }
    }
}

// ---------------------------------------------------------------------------
// Fused K/V projection from srcs (verified R11/R13).
// ---------------------------------------------------------------------------
__global__ __launch_bounds__(256) void gemm_srcs_kv(
    const float* __restrict__ S,
    const __bf16* __restrict__ Wk, const float* __restrict__ bk,
    const __bf16* __restrict__ Wv, const float* __restrict__ bv,
    __bf16* __restrict__ Kout, __bf16* __restrict__ Vt)
{
  extern __shared__ __bf16 lds[];
  __bf16* As = lds;              // [128][264]
  __bf16* Bs = lds + 128*264;    // [64][264]

  const int tid  = threadIdx.x;
  const int wid  = tid >> 6;
  const int lane = tid & 63;
  const int wr   = wid >> 1;
  const int wc   = wid & 1;
  const int lq   = lane & 15;
  const int lk8  = (lane >> 4) << 3;
  const int rb   = (lane >> 4) << 2;

  const int m0 = blockIdx.x * 128;
  const int bb = m0 >> 12;
  const int p0 = m0 & 4095;

  const int cA = tid & 31;
  const int qA = tid >> 5;
  for (int k0=0; k0<256; k0+=32){
    const float* sbase = &S[((size_t)bb*256 + k0 + cA)*4096 + p0];
    #pragma unroll
    for (int ps=0; ps<4; ps++){
      const int p = ps*32 + qA*4;
      const float4 f4 = *(const float4*)(sbase + p);
      As[(p+0)*264 + k0 + cA] = (__bf16)f4.x;
      As[(p+1)*264 + k0 + cA] = (__bf16)f4.y;
      As[(p+2)*264 + k0 + cA] = (__bf16)f4.z;
      As[(p+3)*264 + k0 + cA] = (__bf16)f4.w;
    }
  }

  const int sr  = tid >> 2;
  const int scb = (tid & 3) * 64;

  for (int half=0; half<2; half++){
    const __bf16* W   = half ? Wv : Wk;
    const float* bias = half ? bv : bk;
    for (int nt=0; nt<4; nt++){
      const int n0 = nt*64;
      __syncthreads();
      {
        const __bf16* wp = W + (size_t)(n0+sr)*256 + scb;
        #pragma unroll
        for (int j=0;j<4;j++){
          *(bf16x8*)&Bs[sr*264 + scb + j*16]     = *(const bf16x8*)(wp + j*16);
          *(bf16x8*)&Bs[sr*264 + scb + j*16 + 8] = *(const bf16x8*)(wp + j*16 + 8);
        }
      }
      __syncthreads();
      f32x4 acc[4][2];
      #pragma unroll
      for (int i=0;i<4;i++)
        #pragma unroll
        for (int j=0;j<2;j++) acc[i][j] = f32x4{0.f,0.f,0.f,0.f};
      #pragma unroll
      for (int k0=0; k0<256; k0+=32){
        bf16x8 bfr[2];
        #pragma unroll
        for (int j=0;j<2;j++)
          bfr[j] = *(const bf16x8*)&Bs[(wc*32 + j*16 + lq)*264 + k0 + lk8];
        #pragma unroll
        for (int i=0;i<4;i++){
          const bf16x8 af = *(const bf16x8*)&As[(wr*64 + i*16 + lq)*264 + k0 + lk8];
          acc[i][0] = MFMA16(af, bfr[0], acc[i][0]);
          acc[i][1] = MFMA16(af, bfr[1], acc[i][1]);
        }
      }
      #pragma unroll
      for (int i=0;i<4;i++)
        #pragma unroll
        for (int j=0;j<2;j++){
          const int coln = n0 + wc*32 + j*16 + lq;
          const float bvv = bias[coln];
          if (half){
            bf16x4 hv;
            #pragma unroll
            for (int r=0;r<4;r++) hv[r] = (__bf16)(acc[i][j][r] + bvv);
            *(bf16x4*)&Vt[((size_t)bb*256 + coln)*4096 + p0 + wr*64 + i*16 + rb] = hv;
          } else {
            #pragma unroll
            for (int r=0;r<4;r++){
              const int rowm = m0 + wr*64 + i*16 + rb + r;
              Kout[(size_t)rowm*256 + coln] = (__bf16)(acc[i][j][r] + bvv);
            }
          }
        }
    }
  }
}

// ---------------------------------------------------------------------------
// LN: out = LN(res + x)*g + beta. res f32, x bf16 (projection output).
// ---------------------------------------------------------------------------
__global__ __launch_bounds__(256) void ln_kernel(const float* __restrict__ res,
                                                 const __bf16* __restrict__ x,
                                                 const float* __restrict__ g,
                                                 const float* __restrict__ beta,
                                                 float* __restrict__ out,
                                                 __bf16* __restrict__ outb)
{
  const int row  = blockIdx.x*4 + (threadIdx.x >> 6);
  const int lane = threadIdx.x & 63;
  const int c = lane*4;
  const float4 rv = *(const float4*)&res[(size_t)row*256 + c];
  const bf16x4 xv = *(const bf16x4*)&x[(size_t)row*256 + c];
  float v0=rv.x+(float)xv[0], v1=rv.y+(float)xv[1];
  float v2=rv.z+(float)xv[2], v3=rv.w+(float)xv[3];
  float s = v0+v1+v2+v3;
  #pragma unroll
  for (int off=1; off<64; off<<=1) s += __shfl_xor(s, off);
  const float mean = s * (1.f/256.f);
  const float d0=v0-mean, d1=v1-mean, d2=v2-mean, d3=v3-mean;
  float q = d0*d0 + d1*d1 + d2*d2 + d3*d3;
  #pragma unroll
  for (int off=1; off<64; off<<=1) q += __shfl_xor(q, off);
  const float rstd = rsqrtf(q*(1.f/256.f) + 1e-5f);
  const float4 gv = *(const float4*)&g[c];
  const float4 bv = *(const float4*)&beta[c];
  float4 ov;
  ov.x = d0*rstd*gv.x + bv.x;
  ov.y = d1*rstd*gv.y + bv.y;
  ov.z = d2*rstd*gv.z + bv.z;
  ov.w = d3*rstd*gv.w + bv.w;
  *(float4*)&out[(size_t)row*256 + c] = ov;
  if (outb){
    bf16x4 hv;
    hv[0]=(__bf16)ov.x; hv[1]=(__bf16)ov.y; hv[2]=(__bf16)ov.z; hv[3]=(__bf16)ov.w;
    *(bf16x4*)&outb[(size_t)row*256 + c] = hv;
  }
}

// ---------------------------------------------------------------------------
// Flash self-attention (verified R10-R13).
// ---------------------------------------------------------------------------
__global__ __launch_bounds__(256) void flash_self(
    const __bf16* __restrict__ qks, const __bf16* __restrict__ vts,
    __bf16* __restrict__ sab)
{
  const int qt = blockIdx.x;
  const int b  = blockIdx.y >> 3;
  const int h  = blockIdx.y & 7;
  const int tid  = threadIdx.x;
  const int wid  = tid >> 6;
  const int lane = tid & 63;
  const int lq   = lane & 15;
  const int hi   = lane >> 4;
  const int lk8  = hi << 3;
  const int rb   = hi << 2;
  const float SCALE = 0.17677669529663687f;

  const int qrow = b*1024 + qt*64 + wid*16 + lq;
  const bf16x8 qf = *(const bf16x8*)&qks[(size_t)qrow*512 + h*32 + lk8];

  const __bf16* kb0 = &qks[(size_t)(b*1024 + lq)*512 + 256 + h*32 + lk8];
  const __bf16* vb0 = &vts[(size_t)(b*256 + h*32 + lq)*1024 + lk8];

  const f32x4 Z = {0.f, 0.f, 0.f, 0.f};
  float m = -1e30f, l = 0.f;
  f32x4 o0 = Z, o1 = Z;

  for (int it=0; it<16; ++it){
    const int key0 = it*64;
    f32x4 s4[4];
    #pragma unroll
    for (int kt=0;kt<4;kt++){
      const bf16x8 kf = *(const bf16x8*)(kb0 + (size_t)(key0 + kt*16)*512);
      s4[kt] = MFMA16(kf, qf, Z);
      #pragma unroll
      for (int r=0;r<4;r++) s4[kt][r] *= SCALE;
    }
    float pm = s4[0][0];
    #pragma unroll
    for (int kt=0;kt<4;kt++)
      #pragma unroll
      for (int r=0;r<4;r++) pm = fmaxf(pm, s4[kt][r]);
    pm = fmaxf(pm, __shfl_xor(pm,16));
    pm = fmaxf(pm, __shfl_xor(pm,32));
    if (!__all(pm <= m + 8.f)){
      const float mn = fmaxf(m, pm);
      const float alpha = __expf(m - mn);
      o0[0]*=alpha; o0[1]*=alpha; o0[2]*=alpha; o0[3]*=alpha;
      o1[0]*=alpha; o1[1]*=alpha; o1[2]*=alpha; o1[3]*=alpha;
      l *= alpha;
      m = mn;
    }
    float p[4][4]; float rs = 0.f;
    #pragma unroll
    for (int kt=0;kt<4;kt++)
      #pragma unroll
      for (int r=0;r<4;r++){ p[kt][r] = __expf(s4[kt][r]-m); rs += p[kt][r]; }
    rs += __shfl_xor(rs,16);
    rs += __shfl_xor(rs,32);
    l += rs;
    unsigned pk0[4], pk1[4];
    #pragma unroll
    for (int kt=0;kt<4;kt++){
      pk0[kt] = pack2bf(p[kt][0], p[kt][1]);
      pk1[kt] = pack2bf(p[kt][2], p[kt][3]);
    }
    const int srcA = ((hi&1)<<5) + lq;
    const int srcB = srcA + 16;
    const bool ksel = hi >= 2;
    bf16x8 pf[2];
    #pragma unroll
    for (int ks2=0; ks2<2; ks2++){
      const unsigned a0 = (unsigned)__shfl((int)pk0[2*ks2],   srcA);
      const unsigned a1 = (unsigned)__shfl((int)pk0[2*ks2+1], srcA);
      const unsigned b0 = (unsigned)__shfl((int)pk1[2*ks2],   srcA);
      const unsigned b1 = (unsigned)__shfl((int)pk1[2*ks2+1], srcA);
      const unsigned c0 = (unsigned)__shfl((int)pk0[2*ks2],   srcB);
      const unsigned c1 = (unsigned)__shfl((int)pk0[2*ks2+1], srcB);
      const unsigned d0 = (unsigned)__shfl((int)pk1[2*ks2],   srcB);
      const unsigned d1 = (unsigned)__shfl((int)pk1[2*ks2+1], srcB);
      union { unsigned u[4]; bf16x8 v; } uu;
      uu.u[0] = ksel ? a1 : a0;
      uu.u[1] = ksel ? b1 : b0;
      uu.u[2] = ksel ? c1 : c0;
      uu.u[3] = ksel ? d1 : d0;
      pf[ks2] = uu.v;
    }
    #pragma unroll
    for (int ks2=0; ks2<2; ks2++){
      const bf16x8 vf0 = *(const bf16x8*)(vb0 + key0 + ks2*32);
      const bf16x8 vf1 = *(const bf16x8*)(vb0 + (size_t)16*1024 + key0 + ks2*32);
      o0 = MFMA16(vf0, pf[ks2], o0);
      o1 = MFMA16(vf1, pf[ks2], o1);
    }
  }
  const float inv = 1.f / l;
  bf16x4 w0, w1;
  #pragma unroll
  for (int r=0;r<4;r++){ w0[r] = (__bf16)(o0[r]*inv); w1[r] = (__bf16)(o1[r]*inv); }
  *(bf16x4*)&sab[(size_t)qrow*256 + h*32 + rb]      = w0;
  *(bf16x4*)&sab[(size_t)qrow*256 + h*32 + 16 + rb] = w1;
}

// ---------------------------------------------------------------------------
// Flash cross-attention v6 (R13/R16/R18-verified, KVBLK=64, 4 waves).
// ---------------------------------------------------------------------------
__global__ __launch_bounds__(256, 1) void flash_cross(
    const __bf16* __restrict__ qgm, const __bf16* __restrict__ kg,
    const __bf16* __restrict__ vtg, __bf16* __restrict__ Opart,
    float* __restrict__ ml)
{
  extern __shared__ __bf16 smem[];
  __bf16* Ks = smem;            // [64][256] perm1-swizzled 16B chunks
  __bf16* Vt = smem + 64*256;   // [256][64] perm1-swizzled 16B chunks

  const int bid = blockIdx.x;
  const int xcd = bid & 7;
  const int grp = bid >> 3;
  const int qt  = grp & 7;
  const int pp  = xcd + 8*(grp >> 3);
  const int b   = pp >> 3;
  const int sl  = pp & 7;

  const int tid  = threadIdx.x;
  const int wid  = tid >> 6;
  const int lane = tid & 63;
  const int lq   = lane & 15;
  const int hi   = lane >> 4;
  const int lk8  = hi << 3;
  const int rb   = hi << 2;
  const int p1l  = perm1(lq & 7);

  const int q0 = b*1024 + qt*128 + wid*32;
  bf16x8 qf[2][8];
  #pragma unroll
  for (int g=0; g<2; g++)
    #pragma unroll
    for (int ks=0; ks<8; ks++)
      qf[g][ks] = *(const bf16x8*)&qgm[(size_t)(q0 + g*16 + lq)*256 + ks*32 + lk8];

  const f32x4 Z = {0.f, 0.f, 0.f, 0.f};
  float m[2] = {-1e30f, -1e30f};
  float l[2] = {0.f, 0.f};
  f32x4 o[2][16];
  #pragma unroll
  for (int g=0; g<2; g++)
    #pragma unroll
    for (int nf=0; nf<16; nf++) o[g][nf] = Z;

  const int srow = tid >> 2;
  const int c4   = tid & 3;
  const int p1s  = perm1(srow & 7);

  for (int it=0; it<8; ++it){
    const int key0 = sl*512 + it*64;
    __syncthreads();
    {
      const __bf16* kb = &kg[(size_t)(b*4096 + key0 + srow)*256];
      #pragma unroll
      for (int j=0;j<8;j++){
        const int ch = c4 + j*4;
        *(bf16x8*)&Ks[srow*256 + ((ch ^ p1s)<<3)] = *(const bf16x8*)(kb + ch*8);
      }
    }
    {
      #pragma unroll
      for (int ps=0; ps<4; ps++){
        const int d = srow + ps*64;
        const __bf16* vb = &vtg[(size_t)(b*256 + d)*4096 + key0];
        #pragma unroll
        for (int s2=0;s2<2;s2++){
          const int ch = c4 + s2*4;
          *(bf16x8*)&Vt[d*64 + ((ch ^ p1s)<<3)] = *(const bf16x8*)(vb + ch*8);
        }
      }
    }
    __syncthreads();
    f32x4 s4[2][4];
    #pragma unroll
    for (int g=0; g<2; g++)
      #pragma unroll
      for (int kt=0;kt<4;kt++) s4[g][kt] = Z;
    #pragma unroll
    for (int ks=0; ks<8; ks++){
      #pragma unroll
      for (int kt=0; kt<4; kt++){
        const bf16x8 kf = *(const bf16x8*)&Ks[(kt*16+lq)*256 + (((ks*4+hi) ^ p1l)<<3)];
        s4[0][kt] = MFMA16(kf, qf[0][ks], s4[0][kt]);
        s4[1][kt] = MFMA16(kf, qf[1][ks], s4[1][kt]);
      }
    }
    float pm[2];
    #pragma unroll
    for (int g=0; g<2; g++){
      float v = s4[g][0][0];
      #pragma unroll
      for (int kt=0;kt<4;kt++)
        #pragma unroll
        for (int r=0;r<4;r++) v = fmaxf(v, s4[g][kt][r]);
      v = fmaxf(v, __shfl_xor(v, 16));
      v = fmaxf(v, __shfl_xor(v, 32));
      pm[g] = v;
    }
    const bool need = (pm[0] > m[0] + 8.f) || (pm[1] > m[1] + 8.f);
    if (__any(need)){
      #pragma unroll
      for (int g=0; g<2; g++){
        const float mn = fmaxf(m[g], pm[g]);
        const float alpha = __expf(m[g] - mn);
        #pragma unroll
        for (int nf=0;nf<16;nf++){
          o[g][nf][0]*=alpha; o[g][nf][1]*=alpha;
          o[g][nf][2]*=alpha; o[g][nf][3]*=alpha;
        }
        l[g] *= alpha;
        m[g] = mn;
      }
    }
    bf16x8 pf[2][2];
    #pragma unroll
    for (int g=0; g<2; g++){
      float p[4][4];
      float rs = 0.f;
      #pragma unroll
      for (int kt=0;kt<4;kt++)
        #pragma unroll
        for (int r=0;r<4;r++){ p[kt][r] = __expf(s4[g][kt][r] - m[g]); rs += p[kt][r]; }
      rs += __shfl_xor(rs, 16);
      rs += __shfl_xor(rs, 32);
      l[g] += rs;
      unsigned pk0[4], pk1[4];
      #pragma unroll
      for (int kt=0;kt<4;kt++){
        pk0[kt] = pack2bf(p[kt][0], p[kt][1]);
        pk1[kt] = pack2bf(p[kt][2], p[kt][3]);
      }
      const int srcA = ((hi&1)<<5) + lq;
      const int srcB = srcA + 16;
      const bool ksel = hi >= 2;
      #pragma unroll
      for (int ks2=0; ks2<2; ks2++){
        const unsigned a0 = (unsigned)__shfl((int)pk0[2*ks2],   srcA);
        const unsigned a1 = (unsigned)__shfl((int)pk0[2*ks2+1], srcA);
        const unsigned b0 = (unsigned)__shfl((int)pk1[2*ks2],   srcA);
        const unsigned b1 = (unsigned)__shfl((int)pk1[2*ks2+1], srcA);
        const unsigned c0 = (unsigned)__shfl((int)pk0[2*ks2],   srcB);
        const unsigned c1 = (unsigned)__shfl((int)pk0[2*ks2+1], srcB);
        const unsigned d0 = (unsigned)__shfl((int)pk1[2*ks2],   srcB);
        const unsigned d1 = (unsigned)__shfl((int)pk1[2*ks2+1], srcB);
        union { unsigned u[4]; bf16x8 v; } uu;
        uu.u[0] = ksel ? a1 : a0;
        uu.u[1] = ksel ? b1 : b0;
        uu.u[2] = ksel ? c1 : c0;
        uu.u[3] = ksel ? d1 : d0;
        pf[g][ks2] = uu.v;
      }
    }
    #pragma unroll
    for (int nf=0; nf<16; nf++){
      #pragma unroll
      for (int ks2=0; ks2<2; ks2++){
        const bf16x8 af = *(const bf16x8*)&Vt[(nf*16+lq)*64 + (((ks2*4+hi) ^ p1l)<<3)];
        o[0][nf] = MFMA16(af, pf[0][ks2], o[0][nf]);
        o[1][nf] = MFMA16(af, pf[1][ks2], o[1][nf]);
      }
    }
  }
  #pragma unroll
  for (int g=0; g<2; g++){
    const int row = q0 + g*16 + lq;
    if (hi == 0){
      ml[(size_t)(sl*8192 + row)*2 + 0] = m[g];
      ml[(size_t)(sl*8192 + row)*2 + 1] = l[g];
    }
    #pragma unroll
    for (int nf=0; nf<16; nf++){
      bf16x4 hv;
      #pragma unroll
      for (int r=0;r<4;r++) hv[r] = (__bf16)o[g][nf][r];
      *(bf16x4*)&Opart[(size_t)(sl*8192 + row)*256 + nf*16 + rb] = hv;
    }
  }
}

// ---------------------------------------------------------------------------
// Combine 8 KV-slices, vectorized: 4 rows/block, bf16x4 per thread.
// ---------------------------------------------------------------------------
__global__ __launch_bounds__(256) void combine_kernel(const __bf16* __restrict__ Opart,
                                                      const float* __restrict__ ml,
                                                      __bf16* __restrict__ out)
{
  const int row  = blockIdx.x*4 + (threadIdx.x >> 6);
  const int lane = threadIdx.x & 63;
  const int d = lane*4;
  float mm[8], ll[8];
  #pragma unroll
  for (int s=0;s<8;s++){
    mm[s] = ml[(size_t)(s*8192+row)*2 + 0];
    ll[s] = ml[(size_t)(s*8192+row)*2 + 1];
  }
  float M = mm[0];
  #pragma unroll
  for (int s=1;s<8;s++) M = fmaxf(M, mm[s]);
  float L = 0.f;
  float acc0 = 0.f, acc1 = 0.f, acc2 = 0.f, acc3 = 0.f;
  #pragma unroll
  for (int s=0;s<8;s++){
    const float e = __expf(mm[s]-M);
    L += ll[s]*e;
    const bf16x4 ov = *(const bf16x4*)&Opart[(size_t)(s*8192+row)*256 + d];
    acc0 += e * (float)ov[0];
    acc1 += e * (float)ov[1];
    acc2 += e * (float)ov[2];
    acc3 += e * (float)ov[3];
  }
  const float inv = 1.f / L;
  bf16x4 hv;
  hv[0] = (__bf16)(acc0*inv);
  hv[1] = (__bf16)(acc1*inv);
  hv[2] = (__bf16)(acc2*inv);
  hv[3] = (__bf16)(acc3*inv);
  *(bf16x4*)&out[(size_t)row*256 + d] = hv;
}

// ---------------------------------------------------------------------------
extern "C" void kernel_launch(void* const* d_in, const int* in_sizes, int n_in,
                              void* d_out, int out_size, void* d_ws, size_t ws_size,
                              hipStream_t stream)
{
  (void)in_sizes; (void)n_in; (void)out_size; (void)ws_size;
  const float* tgt        = (const float*)d_in[0];
  const float* srcs       = (const float*)d_in[2];
  const float* posemb     = (const float*)d_in[3];
  const float* in_proj_w  = (const float*)d_in[4];
  const float* in_proj_b  = (const float*)d_in[5];
  const float* out_proj_w = (const float*)d_in[6];
  const float* out_proj_b = (const float*)d_in[7];
  const float* lin_q_w    = (const float*)d_in[8];
  const float* lin_q_b    = (const float*)d_in[9];
  const float* lin_k_w    = (const float*)d_in[10];
  const float* lin_k_b    = (const float*)d_in[11];
  const float* lin_v_w    = (const float*)d_in[12];
  const float* lin_v_b    = (const float*)d_in[13];
  const float* lin_o_w    = (const float*)d_in[14];
  const float* lin_o_b    = (const float*)d_in[15];
  const float* norm1_g    = (const float*)d_in[16];
  const float* norm1_b    = (const float*)d_in[17];
  const float* norm2_g    = (const float*)d_in[18];
  const float* norm2_b    = (const float*)d_in[19];
  const float* ffn_w1     = (const float*)d_in[20];
  const float* ffn_b1     = (const float*)d_in[21];
  const float* ffn_w2     = (const float*)d_in[22];
  const float* ffn_b2     = (const float*)d_in[23];
  const float* ffn_norm_g = (const float*)d_in[24];
  const float* ffn_norm_b = (const float*)d_in[25];
  float* out = (float*)d_out;

  char* w = (char*)d_ws;
  const size_t MB = (size_t)1 << 20;
  // Region plan (R19-audited; saproj/t2proj/ffn_out bf16):
  float*  tgt1    = (float*)(w + 0);
  __bf16* qk_s    = (__bf16*)(w + 8*MB);
  __bf16* query_b = (__bf16*)(w + 8*MB);
  __bf16* tgt1b   = (__bf16*)(w + 12*MB);
  __bf16* attn2   = (__bf16*)(w + 12*MB);
  __bf16* v_t     = (__bf16*)(w + 16*MB);
  __bf16* key_b   = (__bf16*)(w + 16*MB);
  __bf16* t2proj  = (__bf16*)(w + 16*MB);
  __bf16* sa_b    = (__bf16*)(w + 20*MB);
  __bf16* saproj  = (__bf16*)(w + 24*MB);
  float*  tgt3    = (float*)(w + 24*MB);
  __bf16* val_t   = (__bf16*)(w + 32*MB);
  __bf16* ffn_h   = (__bf16*)(w + 32*MB);
  __bf16* Opart   = (__bf16*)(w + 48*MB);
  __bf16* ffn_out = (__bf16*)(w + 48*MB);
  __bf16* tgt3b   = (__bf16*)(w + 56*MB);
  float*  ml      = (float*)(w + 80*MB);
  __bf16* wb      = (__bf16*)(w + 81*MB);

  __bf16* wb_inproj = wb;
  __bf16* wb_outp   = wb + 196608;
  __bf16* wb_q      = wb + 262144;
  __bf16* wb_k      = wb + 327680;
  __bf16* wb_v      = wb + 393216;
  __bf16* wb_o      = wb + 458752;
  __bf16* wb_ff1    = wb + 524288;
  __bf16* wb_ff2    = wb + 786432;

  // 0: one-shot weight conversion
  cvt_weights<<<1024,256,0,stream>>>(in_proj_w, out_proj_w, lin_q_w, lin_k_w,
      lin_v_w, lin_o_w, ffn_w1, ffn_w2, wb);

  // ---- Stage A: self-attention ----
  gemm_bt<64,false,1,1,1><<<dim3(128,8),256,0,stream>>>(tgt, posemb,
      wb_inproj, in_proj_b, qk_s, 8192,512,256, 512,0, 1.f);
  gemm_bt<64,false,2,0,1><<<dim3(128,4),256,0,stream>>>(tgt, nullptr,
      wb_inproj + (size_t)512*256, in_proj_b + 512, v_t, 8192,256,256, 256,0, 1.f);
  flash_self<<<dim3(16,64),256,0,stream>>>(qk_s, v_t, sa_b);
  gemm_bt<64,false,1,2,1><<<dim3(128,4),256,0,stream>>>(sa_b, nullptr,
      wb_outp, out_proj_b, saproj, 8192,256,256, 256,0, 1.f);
  ln_kernel<<<2048,256,0,stream>>>(tgt, saproj, norm2_g, norm2_b, tgt1, tgt1b);

  // ---- Stage B: cross-attention ----
  gemm_bt<64,false,1,2,1><<<dim3(128,4),256,0,stream>>>(tgt1b, nullptr,
      wb_q, lin_q_b, query_b, 8192,256,256, 256,0, 1.f);
  gemm_srcs_kv<<<256,256,(128+64)*264*2,stream>>>(srcs,
      wb_k, lin_k_b, wb_v, lin_v_b, key_b, val_t);
  flash_cross<<<512,256,65536,stream>>>(query_b, key_b, val_t, Opart, ml);
  combine_kernel<<<2048,256,0,stream>>>(Opart, ml, attn2);
  gemm_bt<64,false,1,2,1><<<dim3(128,4),256,0,stream>>>(attn2, nullptr,
      wb_o, lin_o_b, t2proj, 8192,256,256, 256,0, 1.f);
  ln_kernel<<<2048,256,0,stream>>>(tgt1, t2proj, norm1_g, norm1_b, tgt3, tgt3b);

  // ---- Stage C: FFN ----
  gemm_bt<128,true,1,2,1><<<dim3(64,16),256,0,stream>>>(tgt3b, nullptr,
      wb_ff1, ffn_b1, ffn_h, 8192,1024,256, 1024,0, 1.f);
  gemm_bt<64,false,1,2,1><<<dim3(128,4),256,0,stream>>>(ffn_h, nullptr,
      wb_ff2, ffn_b2, ffn_out, 8192,256,1024, 256,0, 1.f);
  ln_kernel<<<2048,256,0,stream>>>(tgt3, ffn_out, ffn_norm_g, ffn_norm_b, out, nullptr);
}